// Round 2
// baseline (536.945 us; speedup 1.0000x reference)
//
#include <hip/hip_runtime.h>
#include <cstdint>
#include <cmath>

typedef short s16x8 __attribute__((ext_vector_type(8)));
typedef float f32x4 __attribute__((ext_vector_type(4)));
typedef float f32x16 __attribute__((ext_vector_type(16)));
typedef int   i32x4 __attribute__((ext_vector_type(4)));
typedef unsigned short u16;

#define E_DIM 2048
#define SEQ   2048
#define NB    2
#define NH    16
#define HD    128
#define BS_TOT 4096   // NB*SEQ

__device__ __forceinline__ u16 f2bf(float f) {
  unsigned u = __float_as_uint(f);
  u += 0x7fffu + ((u >> 16) & 1u);
  return (u16)(u >> 16);
}
__device__ __forceinline__ float bf2f(u16 h) {
  return __uint_as_float(((unsigned)h) << 16);
}
__device__ __forceinline__ float rmax16(float v) {
  v = fmaxf(v, __shfl_xor(v, 1));
  v = fmaxf(v, __shfl_xor(v, 2));
  v = fmaxf(v, __shfl_xor(v, 4));
  v = fmaxf(v, __shfl_xor(v, 8));
  return v;
}
__device__ __forceinline__ float rsum16(float v) {
  v += __shfl_xor(v, 1);
  v += __shfl_xor(v, 2);
  v += __shfl_xor(v, 4);
  v += __shfl_xor(v, 8);
  return v;
}

// async global->LDS, 16B per lane. LDS dest is wave-uniform base + lane*16;
// swizzle goes into the GLOBAL pointer.
__device__ __forceinline__ void gll16(const u16* g, u16* l) {
  __builtin_amdgcn_global_load_lds(
      (const __attribute__((address_space(1))) void*)g,
      (__attribute__((address_space(3))) void*)l, 16, 0, 0);
}

// ---------------- cast fp32 -> bf16, 8 elements/thread ----------------
__global__ __launch_bounds__(256) void cast_kernel(const float* __restrict__ in,
                                                   u16* __restrict__ out) {
  const size_t t = (size_t)blockIdx.x * 256 + threadIdx.x;
  const float* p = in + t * 8;
  f32x4 a = *(const f32x4*)p;
  f32x4 b = *(const f32x4*)(p + 4);
  union { u16 u[8]; i32x4 v; } r;
  r.u[0] = f2bf(a[0]); r.u[1] = f2bf(a[1]); r.u[2] = f2bf(a[2]); r.u[3] = f2bf(a[3]);
  r.u[4] = f2bf(b[0]); r.u[5] = f2bf(b[1]); r.u[6] = f2bf(b[2]); r.u[7] = f2bf(b[3]);
  *(i32x4*)(out + t * 8) = r.v;
}

// two-array cast in one dispatch (blocks [0,half) -> 0, [half,2*half) -> 1)
__global__ __launch_bounds__(256) void cast2_kernel(const float* __restrict__ in0,
                                                    u16* __restrict__ out0,
                                                    const float* __restrict__ in1,
                                                    u16* __restrict__ out1,
                                                    int half) {
  const int bsel = blockIdx.x >= half;
  const float* in = bsel ? in1 : in0;
  u16* out = bsel ? out1 : out0;
  const size_t t = (size_t)(blockIdx.x - (bsel ? half : 0)) * 256 + threadIdx.x;
  const float* p = in + t * 8;
  f32x4 a = *(const f32x4*)p;
  f32x4 b = *(const f32x4*)(p + 4);
  union { u16 u[8]; i32x4 v; } r;
  r.u[0] = f2bf(a[0]); r.u[1] = f2bf(a[1]); r.u[2] = f2bf(a[2]); r.u[3] = f2bf(a[3]);
  r.u[4] = f2bf(b[0]); r.u[5] = f2bf(b[1]); r.u[6] = f2bf(b[2]); r.u[7] = f2bf(b[3]);
  *(i32x4*)(out + t * 8) = r.v;
}

// ---------------- NT GEMM: C[M,N] = A[M,K] * B[N,K]^T  (32x32x16 MFMA) -------
// 128x128 tile, BK=64, global_load_lds 16B staging, chunk swizzle via global
// pointer (gq = c ^ (r&7)). Wave tile 64x64 = 2x2 of 32x32x16.
// A/B frag: m|n = lane&31, k = (lane>>5)*8+j; C/D: col=lane&31,
// row = (reg&3)+8*(reg>>2)+4*(lane>>5)  [m74/m101-verified].
// CVTA: A is fp32 converted during VGPR staging (Wv GEMM only).
template <typename OT, bool CVTA>
__global__ __launch_bounds__(256) void gemm_nt(const void* __restrict__ Av,
                                               const u16* __restrict__ B,
                                               OT* __restrict__ C,
                                               int M, int N, int K) {
  __shared__ __align__(16) u16 As[128 * 64];
  __shared__ __align__(16) u16 Bs[128 * 64];
  const int t  = threadIdx.x;
  const int w  = t >> 6, l = t & 63;
  const int l31 = l & 31, lh = l >> 5;
  const int wr = w >> 1, wc = w & 1;
  const int m0 = blockIdx.y * 128, n0 = blockIdx.x * 128;

  f32x16 acc[2][2];
#pragma unroll
  for (int mi = 0; mi < 2; ++mi)
#pragma unroll
    for (int ni = 0; ni < 2; ++ni)
#pragma unroll
      for (int e = 0; e < 16; ++e) acc[mi][ni][e] = 0.f;

  for (int k0 = 0; k0 < K; k0 += 64) {
    __syncthreads();
    if constexpr (CVTA) {
      const float* A = (const float*)Av;
#pragma unroll
      for (int i = 0; i < 4; ++i) {
        const int ci = i * 256 + t;
        const int r = ci >> 3, c = ci & 7, gq = c ^ (r & 7);
        const float* s = A + (size_t)(m0 + r) * K + k0 + gq * 8;
        f32x4 a = *(const f32x4*)s;
        f32x4 b = *(const f32x4*)(s + 4);
        union { u16 u[8]; i32x4 v; } rr;
        rr.u[0] = f2bf(a[0]); rr.u[1] = f2bf(a[1]); rr.u[2] = f2bf(a[2]); rr.u[3] = f2bf(a[3]);
        rr.u[4] = f2bf(b[0]); rr.u[5] = f2bf(b[1]); rr.u[6] = f2bf(b[2]); rr.u[7] = f2bf(b[3]);
        *(i32x4*)(As + ci * 8) = rr.v;
      }
    } else {
      const u16* A = (const u16*)Av;
#pragma unroll
      for (int i = 0; i < 4; ++i) {
        const int ci = i * 256 + t;
        const int r = ci >> 3, c = ci & 7, gq = c ^ (r & 7);
        gll16(A + (size_t)(m0 + r) * K + k0 + gq * 8, As + ci * 8);
      }
    }
#pragma unroll
    for (int i = 0; i < 4; ++i) {
      const int ci = i * 256 + t;
      const int r = ci >> 3, c = ci & 7, gq = c ^ (r & 7);
      gll16(B + (size_t)(n0 + r) * K + k0 + gq * 8, Bs + ci * 8);
    }
    __syncthreads();
#pragma unroll
    for (int ks = 0; ks < 4; ++ks) {   // K=16 per step
      const int chunk = ks * 2 + lh;
      s16x8 af[2], bf[2];
#pragma unroll
      for (int mi = 0; mi < 2; ++mi) {
        const int ra = wr * 64 + mi * 32 + l31;
        af[mi] = *(const s16x8*)(As + ra * 64 + ((chunk ^ (ra & 7)) << 3));
      }
#pragma unroll
      for (int ni = 0; ni < 2; ++ni) {
        const int rb = wc * 64 + ni * 32 + l31;
        bf[ni] = *(const s16x8*)(Bs + rb * 64 + ((chunk ^ (rb & 7)) << 3));
      }
#pragma unroll
      for (int mi = 0; mi < 2; ++mi)
#pragma unroll
        for (int ni = 0; ni < 2; ++ni)
          acc[mi][ni] = __builtin_amdgcn_mfma_f32_32x32x16_bf16(af[mi], bf[ni], acc[mi][ni], 0, 0, 0);
    }
  }

#pragma unroll
  for (int mi = 0; mi < 2; ++mi)
#pragma unroll
    for (int ni = 0; ni < 2; ++ni) {
      const int col = n0 + wc * 64 + ni * 32 + l31;
#pragma unroll
      for (int reg = 0; reg < 16; ++reg) {
        const int row = m0 + wr * 64 + mi * 32 + 4 * lh + (reg & 3) + 8 * (reg >> 2);
        const float v = acc[mi][ni][reg];
        if constexpr (sizeof(OT) == 2) {
          C[(size_t)row * N + col] = (OT)f2bf(v);
        } else {
          C[(size_t)row * N + col] = v;
        }
      }
    }
}

// ---------------- merged Q+K GEMM (32x32x16, BK=64) ----------------
// grid dim(32,32) = 1024 blocks: bx<16 computes Q tile, bx>=16 computes K tile.
__global__ __launch_bounds__(256) void gemm_qk(const u16* __restrict__ A,
                                               const u16* __restrict__ B0,
                                               const u16* __restrict__ B1,
                                               u16* __restrict__ C0,
                                               u16* __restrict__ C1) {
  constexpr int K = 2048, N = 2048;
  __shared__ __align__(16) u16 As[128 * 64];
  __shared__ __align__(16) u16 Bs[128 * 64];
  const int bx = blockIdx.x;
  const u16* B = (bx >> 4) ? B1 : B0;
  u16* C = (bx >> 4) ? C1 : C0;
  const int n0 = (bx & 15) * 128, m0 = blockIdx.y * 128;
  const int t  = threadIdx.x;
  const int w  = t >> 6, l = t & 63;
  const int l31 = l & 31, lh = l >> 5;
  const int wr = w >> 1, wc = w & 1;

  f32x16 acc[2][2];
#pragma unroll
  for (int mi = 0; mi < 2; ++mi)
#pragma unroll
    for (int ni = 0; ni < 2; ++ni)
#pragma unroll
      for (int e = 0; e < 16; ++e) acc[mi][ni][e] = 0.f;

  for (int k0 = 0; k0 < K; k0 += 64) {
    __syncthreads();
#pragma unroll
    for (int i = 0; i < 4; ++i) {
      const int ci = i * 256 + t;
      const int r = ci >> 3, c = ci & 7, gq = c ^ (r & 7);
      gll16(A + (size_t)(m0 + r) * K + k0 + gq * 8, As + ci * 8);
    }
#pragma unroll
    for (int i = 0; i < 4; ++i) {
      const int ci = i * 256 + t;
      const int r = ci >> 3, c = ci & 7, gq = c ^ (r & 7);
      gll16(B + (size_t)(n0 + r) * K + k0 + gq * 8, Bs + ci * 8);
    }
    __syncthreads();
#pragma unroll
    for (int ks = 0; ks < 4; ++ks) {
      const int chunk = ks * 2 + lh;
      s16x8 af[2], bf[2];
#pragma unroll
      for (int mi = 0; mi < 2; ++mi) {
        const int ra = wr * 64 + mi * 32 + l31;
        af[mi] = *(const s16x8*)(As + ra * 64 + ((chunk ^ (ra & 7)) << 3));
      }
#pragma unroll
      for (int ni = 0; ni < 2; ++ni) {
        const int rb = wc * 64 + ni * 32 + l31;
        bf[ni] = *(const s16x8*)(Bs + rb * 64 + ((chunk ^ (rb & 7)) << 3));
      }
#pragma unroll
      for (int mi = 0; mi < 2; ++mi)
#pragma unroll
        for (int ni = 0; ni < 2; ++ni)
          acc[mi][ni] = __builtin_amdgcn_mfma_f32_32x32x16_bf16(af[mi], bf[ni], acc[mi][ni], 0, 0, 0);
    }
  }

#pragma unroll
  for (int mi = 0; mi < 2; ++mi)
#pragma unroll
    for (int ni = 0; ni < 2; ++ni) {
      const int col = n0 + wc * 64 + ni * 32 + l31;
#pragma unroll
      for (int reg = 0; reg < 16; ++reg) {
        const int row = m0 + wr * 64 + mi * 32 + 4 * lh + (reg & 3) + 8 * (reg >> 2);
        C[(size_t)row * N + col] = f2bf(acc[mi][ni][reg]);
      }
    }
}

// ---------------- RoPE (interleaved) on q and k, in place, bf16 ----------------
// Q is additionally pre-scaled by rsqrt(128)*log2(e): scores arrive in exp2 domain.
__global__ __launch_bounds__(256) void rope_kernel(u16* __restrict__ q, u16* __restrict__ k) {
  const float QS = 0.08838834764831845f * 1.4426950408889634f;
  const size_t t = (size_t)blockIdx.x * 256 + threadIdx.x;
  const size_t e8 = t * 8;
  const int col = (int)(e8 & (E_DIM - 1));
  const int row = (int)(e8 >> 11);
  const int s   = row & (SEQ - 1);
  const int d   = col & (HD - 1);
  float cs[4], sn[4];
#pragma unroll
  for (int j = 0; j < 4; ++j) {
    const float inv = exp2f(-0.20762050593046014f * (float)((d >> 1) + j));
    const float ang = (float)s * inv;
    sincosf(ang, &sn[j], &cs[j]);
  }
  u16* qp = q + e8;
  u16* kp = k + e8;
  union { u16 u[8]; i32x4 v; } a, b;
  a.v = *(const i32x4*)qp;
  b.v = *(const i32x4*)kp;
#pragma unroll
  for (int j = 0; j < 4; ++j) {
    const float csq = cs[j] * QS, snq = sn[j] * QS;
    const float q1 = bf2f(a.u[2 * j]), q2 = bf2f(a.u[2 * j + 1]);
    const float k1 = bf2f(b.u[2 * j]), k2 = bf2f(b.u[2 * j + 1]);
    a.u[2 * j]     = f2bf(q1 * csq - q2 * snq);
    a.u[2 * j + 1] = f2bf(q1 * snq + q2 * csq);
    b.u[2 * j]     = f2bf(k1 * cs[j] - k2 * sn[j]);
    b.u[2 * j + 1] = f2bf(k1 * sn[j] + k2 * cs[j]);
  }
  *(i32x4*)qp = a.v;
  *(i32x4*)kp = b.v;
}

// ---------------- causal flash attention v6: 2 blocks/CU for latency hiding ----
// QBLK=128 (8 waves x 16 q-rows), KVBLK=64, double-buffered. LDS 64 KiB =
// 2 x (K 16K | V 16K) -> 2 blocks/CU = 4 waves/SIMD (v5 was 1 block/CU, both
// pipes <50% busy, latency-bound). Independent co-resident blocks overlap each
// other's barrier/softmax-chain stalls. Paired q-tiles (15-j, j) -> uniform 34
// tile-iters/block. Prefetch next KV tile + s_waitcnt vmcnt(4) (never 0
// mid-loop) + raw s_barrier. P (16x64/wave, 2KB) overlays dead K region of the
// current buffer (8 waves x 2KB = 16KB exactly). Diag masking on the last TWO
// tiles (64-wide tiles are triangular per wave-half at QBLK=128).
// XCD-grouped decode: all 16 j-blocks of one (b,h) share bx%8 -> same XCD L2.
__global__ __launch_bounds__(512, 4) void flash_kernel(const u16* __restrict__ q,
                                                       const u16* __restrict__ kmat,
                                                       const u16* __restrict__ vt,
                                                       u16* __restrict__ attn) {
  __shared__ __align__(16) u16 KV[32768];  // 64 KiB: buf0 K|V, buf1 K|V
  const int bx = blockIdx.x;
  const int j  = bx >> 5;                        // 0..15 paired-tile index
  const int bh = (bx & 7) * 4 + ((bx >> 3) & 3); // 0..31, constant bx%8 per (b,h)
  const int b  = bh >> 4, h = bh & 15;
  const int t = threadIdx.x, w = t >> 6, l = t & 63, lq = l >> 4, lm = l & 15;

  const u16* kbase = kmat + (size_t)(b * SEQ) * E_DIM + h * HD;
  const u16* vbase = vt + (size_t)(h * HD) * BS_TOT + (size_t)b * SEQ;
  const f32x4 fzero = {0.f, 0.f, 0.f, 0.f};

  auto stage = [&](int it) {
    const int base = (it & 1) << 14;  // buffer select (u16 units, 16384 apart)
    const int k0 = it * 64;
#pragma unroll
    for (int i = 0; i < 2; ++i) {     // K tile: 64(s) x 128(d) bf16 = 16 KB
      const int ci = i * 512 + t;
      const int r = ci >> 4, gq = (ci & 15) ^ (r & 15);
      gll16(kbase + (size_t)(k0 + r) * E_DIM + gq * 8, KV + base + ci * 8);
    }
#pragma unroll
    for (int i = 0; i < 2; ++i) {     // V^T tile: 128(d) x 64(s) bf16 = 16 KB
      const int ci = i * 512 + t;
      const int r = ci >> 3, gq = (ci & 7) ^ (r & 7);
      gll16(vbase + (size_t)r * BS_TOT + k0 + gq * 8, KV + base + 8192 + ci * 8);
    }
  };

  for (int pass = 0; pass < 2; ++pass) {
    const int qt = pass ? j : (15 - j);
    const int q0 = qt * 128;
    const int nT = 2 * qt + 2;

    stage(0);  // prologue: tile 0 into buf0 (pass 1: after end-of-loop barrier)

    const u16* qp = q + (size_t)(b * SEQ + q0 + w * 16) * E_DIM + h * HD;
    s16x8 qf[4];
#pragma unroll
    for (int kx = 0; kx < 4; ++kx)
      qf[kx] = *(const s16x8*)(qp + (size_t)lm * E_DIM + kx * 32 + lq * 8);

    float m_i[4], l_i[4];
    f32x4 acc_o[8];
#pragma unroll
    for (int rr = 0; rr < 4; ++rr) { m_i[rr] = -1e30f; l_i[rr] = 0.f; }
#pragma unroll
    for (int nd = 0; nd < 8; ++nd) acc_o[nd] = fzero;

    for (int it = 0; it < nT; ++it) {
      const int base = (it & 1) << 14;
      const int k0 = it * 64;
      // prefetch next tile; wait only for OWN tile's 4 loads (counted vmcnt)
      if (it + 1 < nT) {
        stage(it + 1);
        asm volatile("s_waitcnt vmcnt(4)" ::: "memory");
      } else {
        asm volatile("s_waitcnt vmcnt(0)" ::: "memory");
      }
      asm volatile("s_barrier" ::: "memory");  // (a) buf[it&1] staged block-wide

      // S = Q K^T  (per wave: 16 x 64), scores pre-scaled into exp2 domain
      f32x4 sc[4];
#pragma unroll
      for (int ni = 0; ni < 4; ++ni) sc[ni] = fzero;
      __builtin_amdgcn_s_setprio(1);
#pragma unroll
      for (int kx = 0; kx < 4; ++kx) {
        s16x8 kf[4];
#pragma unroll
        for (int ni = 0; ni < 4; ++ni) {
          const int rn = ni * 16 + lm;
          kf[ni] = *(const s16x8*)(KV + base + rn * 128 + (((kx * 4 + lq) ^ lm) << 3));
        }
#pragma unroll
        for (int ni = 0; ni < 4; ++ni)
          sc[ni] = __builtin_amdgcn_mfma_f32_16x16x32_bf16(qf[kx], kf[ni], sc[ni], 0, 0, 0);
      }
      __builtin_amdgcn_s_setprio(0);

      // online softmax (exp2 domain); last TWO tiles need diag masking
      const bool diag = (it >= nT - 2);
#pragma unroll
      for (int rr = 0; rr < 4; ++rr) {
        const int qrow = q0 + w * 16 + lq * 4 + rr;
        float mt = -1e30f;
#pragma unroll
        for (int ni = 0; ni < 4; ++ni) {
          float s = sc[ni][rr];
          if (diag && (k0 + ni * 16 + lm) > qrow) s = -1e30f;
          sc[ni][rr] = s;
          mt = fmaxf(mt, s);
        }
        mt = rmax16(mt);
        const float mn = fmaxf(m_i[rr], mt);
        const float al = exp2f(m_i[rr] - mn);
        float rs = 0.f;
#pragma unroll
        for (int ni = 0; ni < 4; ++ni) {
          const float p = exp2f(sc[ni][rr] - mn);
          sc[ni][rr] = p;
          rs += p;
        }
        rs = rsum16(rs);
        l_i[rr] = l_i[rr] * al + rs;
        m_i[rr] = mn;
#pragma unroll
        for (int nd = 0; nd < 8; ++nd) acc_o[nd][rr] *= al;
      }

      asm volatile("s_barrier" ::: "memory");  // (b) all waves' K reads retired
      u16* P = KV + base + w * 1024;           // overlay dead K region, per wave
#pragma unroll
      for (int rr = 0; rr < 4; ++rr) {
        const int r = lq * 4 + rr;
#pragma unroll
        for (int ni = 0; ni < 4; ++ni) {
          const int c = ni * 16 + lm;
          P[r * 64 + (((c >> 3) ^ (r & 7)) << 3) + (c & 7)] = f2bf(sc[ni][rr]);
        }
      }

      // O += P V  (own-wave P slice: lgkmcnt ordering, no extra barrier)
      __builtin_amdgcn_s_setprio(1);
#pragma unroll
      for (int kx = 0; kx < 2; ++kx) {
        const s16x8 pf = *(const s16x8*)(P + lm * 64 + (((kx * 4 + lq) ^ (lm & 7)) << 3));
#pragma unroll
        for (int nd = 0; nd < 8; ++nd) {
          const int rn = nd * 16 + lm;
          const s16x8 vf = *(const s16x8*)(KV + base + 8192 + rn * 64 + (((kx * 4 + lq) ^ (lm & 7)) << 3));
          acc_o[nd] = __builtin_amdgcn_mfma_f32_16x16x32_bf16(pf, vf, acc_o[nd], 0, 0, 0);
        }
      }
      __builtin_amdgcn_s_setprio(0);

      asm volatile("s_barrier" ::: "memory");  // (c) buf consumed; next stage safe
    }

    // epilogue for this pass: normalize and store bf16
    u16* op = attn + (size_t)(b * SEQ + q0 + w * 16) * E_DIM + h * HD;
#pragma unroll
    for (int rr = 0; rr < 4; ++rr) {
      const float inv = 1.0f / l_i[rr];
      const int row = lq * 4 + rr;
#pragma unroll
      for (int nd = 0; nd < 8; ++nd) {
        const int colc = nd * 16 + lm;
        op[(size_t)row * E_DIM + colc] = f2bf(acc_o[nd][rr] * inv);
      }
    }
  }
}

// ---------------- launch ----------------
// ws 32 MiB: xb @0 (16M, reused as attn), vslot @16M (16M): Wq_bf+Wk_bf copies,
// then V^T (overwrites them), then Wo_bf. d_out scratch: qb @0, kb @+16M.
extern "C" void kernel_launch(void* const* d_in, const int* in_sizes, int n_in,
                              void* d_out, int out_size, void* d_ws, size_t ws_size,
                              hipStream_t stream) {
  const float* x  = (const float*)d_in[0];
  const float* Wq = (const float*)d_in[1];
  const float* Wk = (const float*)d_in[2];
  const float* Wv = (const float*)d_in[3];
  const float* Wo = (const float*)d_in[4];
  float* out = (float*)d_out;
  char* ws = (char*)d_ws;

  u16* xb    = (u16*)(ws);                         // 16 MiB
  u16* vslot = (u16*)(ws + (size_t)16 * 1048576);  // 16 MiB
  u16* wq_bf = vslot;                              // 8 MiB (dead after gemm_qk)
  u16* wk_bf = vslot + (size_t)4 * 1048576;        // 8 MiB (dead after gemm_qk)
  u16* vtb   = vslot;                              // V^T [E][B*S]
  u16* wo_bf = vslot;                              // Wo bf16 (after flash)
  u16* qb    = (u16*)d_out;                        // 16 MiB scratch in d_out
  u16* kb    = (u16*)d_out + (size_t)8 * 1048576;  // 16 MiB scratch in d_out
  u16* attnb = xb;

  (void)in_sizes; (void)n_in; (void)out_size; (void)ws_size;

  cast_kernel<<<4096, 256, 0, stream>>>(x, xb);
  cast2_kernel<<<4096, 256, 0, stream>>>(Wq, wq_bf, Wk, wk_bf, 2048);
  gemm_qk<<<dim3(32, 32), 256, 0, stream>>>(xb, wq_bf, wk_bf, qb, kb);
  // V^T[e][s] = Wv[e][:] . x[s][:]  (A = Wv fp32 converted on stage, B = xb)
  gemm_nt<u16, true><<<dim3(32, 16), 256, 0, stream>>>(Wv, xb, vtb, 2048, 4096, 2048);
  rope_kernel<<<4096, 256, 0, stream>>>(qb, kb);
  flash_kernel<<<512, 512, 0, stream>>>(qb, kb, vtb, attnb);
  cast_kernel<<<2048, 256, 0, stream>>>(Wo, wo_bf);
  gemm_nt<float, false><<<dim3(16, 32), 256, 0, stream>>>(attnb, wo_bf, out, 4096, 2048, 2048);
}

// Round 3
// 520.080 us; speedup vs baseline: 1.0324x; 1.0324x over previous
//
#include <hip/hip_runtime.h>
#include <cstdint>
#include <cmath>

typedef short s16x8 __attribute__((ext_vector_type(8)));
typedef float f32x4 __attribute__((ext_vector_type(4)));
typedef float f32x16 __attribute__((ext_vector_type(16)));
typedef int   i32x4 __attribute__((ext_vector_type(4)));
typedef unsigned short u16;

#define E_DIM 2048
#define SEQ   2048
#define NB    2
#define NH    16
#define HD    128
#define BS_TOT 4096   // NB*SEQ

__device__ __forceinline__ u16 f2bf(float f) {
  unsigned u = __float_as_uint(f);
  u += 0x7fffu + ((u >> 16) & 1u);
  return (u16)(u >> 16);
}
__device__ __forceinline__ float bf2f(u16 h) {
  return __uint_as_float(((unsigned)h) << 16);
}
__device__ __forceinline__ float rmax16(float v) {
  v = fmaxf(v, __shfl_xor(v, 1));
  v = fmaxf(v, __shfl_xor(v, 2));
  v = fmaxf(v, __shfl_xor(v, 4));
  v = fmaxf(v, __shfl_xor(v, 8));
  return v;
}
__device__ __forceinline__ float rsum16(float v) {
  v += __shfl_xor(v, 1);
  v += __shfl_xor(v, 2);
  v += __shfl_xor(v, 4);
  v += __shfl_xor(v, 8);
  return v;
}

// async global->LDS, 16B per lane. LDS dest is wave-uniform base + lane*16;
// swizzle goes into the GLOBAL pointer.
__device__ __forceinline__ void gll16(const u16* g, u16* l) {
  __builtin_amdgcn_global_load_lds(
      (const __attribute__((address_space(1))) void*)g,
      (__attribute__((address_space(3))) void*)l, 16, 0, 0);
}

// ---------------- cast fp32 -> bf16, 8 elements/thread ----------------
__global__ __launch_bounds__(256) void cast_kernel(const float* __restrict__ in,
                                                   u16* __restrict__ out) {
  const size_t t = (size_t)blockIdx.x * 256 + threadIdx.x;
  const float* p = in + t * 8;
  f32x4 a = *(const f32x4*)p;
  f32x4 b = *(const f32x4*)(p + 4);
  union { u16 u[8]; i32x4 v; } r;
  r.u[0] = f2bf(a[0]); r.u[1] = f2bf(a[1]); r.u[2] = f2bf(a[2]); r.u[3] = f2bf(a[3]);
  r.u[4] = f2bf(b[0]); r.u[5] = f2bf(b[1]); r.u[6] = f2bf(b[2]); r.u[7] = f2bf(b[3]);
  *(i32x4*)(out + t * 8) = r.v;
}

// two-array cast in one dispatch (blocks [0,half) -> 0, [half,2*half) -> 1)
__global__ __launch_bounds__(256) void cast2_kernel(const float* __restrict__ in0,
                                                    u16* __restrict__ out0,
                                                    const float* __restrict__ in1,
                                                    u16* __restrict__ out1,
                                                    int half) {
  const int bsel = blockIdx.x >= half;
  const float* in = bsel ? in1 : in0;
  u16* out = bsel ? out1 : out0;
  const size_t t = (size_t)(blockIdx.x - (bsel ? half : 0)) * 256 + threadIdx.x;
  const float* p = in + t * 8;
  f32x4 a = *(const f32x4*)p;
  f32x4 b = *(const f32x4*)(p + 4);
  union { u16 u[8]; i32x4 v; } r;
  r.u[0] = f2bf(a[0]); r.u[1] = f2bf(a[1]); r.u[2] = f2bf(a[2]); r.u[3] = f2bf(a[3]);
  r.u[4] = f2bf(b[0]); r.u[5] = f2bf(b[1]); r.u[6] = f2bf(b[2]); r.u[7] = f2bf(b[3]);
  *(i32x4*)(out + t * 8) = r.v;
}

// ---------------- NT GEMM: C[M,N] = A[M,K] * B[N,K]^T  (32x32x16 MFMA) -------
// 128x128 tile, BK=64, global_load_lds 16B staging, chunk swizzle via global
// pointer (gq = c ^ (r&7)). Wave tile 64x64 = 2x2 of 32x32x16.
// A/B frag: m|n = lane&31, k = (lane>>5)*8+j; C/D: col=lane&31,
// row = (reg&3)+8*(reg>>2)+4*(lane>>5)  [m74/m101-verified].
// CVTA: A is fp32 converted during VGPR staging (Wv GEMM only).
template <typename OT, bool CVTA>
__global__ __launch_bounds__(256) void gemm_nt(const void* __restrict__ Av,
                                               const u16* __restrict__ B,
                                               OT* __restrict__ C,
                                               int M, int N, int K) {
  __shared__ __align__(16) u16 As[128 * 64];
  __shared__ __align__(16) u16 Bs[128 * 64];
  const int t  = threadIdx.x;
  const int w  = t >> 6, l = t & 63;
  const int l31 = l & 31, lh = l >> 5;
  const int wr = w >> 1, wc = w & 1;
  const int m0 = blockIdx.y * 128, n0 = blockIdx.x * 128;

  f32x16 acc[2][2];
#pragma unroll
  for (int mi = 0; mi < 2; ++mi)
#pragma unroll
    for (int ni = 0; ni < 2; ++ni)
#pragma unroll
      for (int e = 0; e < 16; ++e) acc[mi][ni][e] = 0.f;

  for (int k0 = 0; k0 < K; k0 += 64) {
    __syncthreads();
    if constexpr (CVTA) {
      const float* A = (const float*)Av;
#pragma unroll
      for (int i = 0; i < 4; ++i) {
        const int ci = i * 256 + t;
        const int r = ci >> 3, c = ci & 7, gq = c ^ (r & 7);
        const float* s = A + (size_t)(m0 + r) * K + k0 + gq * 8;
        f32x4 a = *(const f32x4*)s;
        f32x4 b = *(const f32x4*)(s + 4);
        union { u16 u[8]; i32x4 v; } rr;
        rr.u[0] = f2bf(a[0]); rr.u[1] = f2bf(a[1]); rr.u[2] = f2bf(a[2]); rr.u[3] = f2bf(a[3]);
        rr.u[4] = f2bf(b[0]); rr.u[5] = f2bf(b[1]); rr.u[6] = f2bf(b[2]); rr.u[7] = f2bf(b[3]);
        *(i32x4*)(As + ci * 8) = rr.v;
      }
    } else {
      const u16* A = (const u16*)Av;
#pragma unroll
      for (int i = 0; i < 4; ++i) {
        const int ci = i * 256 + t;
        const int r = ci >> 3, c = ci & 7, gq = c ^ (r & 7);
        gll16(A + (size_t)(m0 + r) * K + k0 + gq * 8, As + ci * 8);
      }
    }
#pragma unroll
    for (int i = 0; i < 4; ++i) {
      const int ci = i * 256 + t;
      const int r = ci >> 3, c = ci & 7, gq = c ^ (r & 7);
      gll16(B + (size_t)(n0 + r) * K + k0 + gq * 8, Bs + ci * 8);
    }
    __syncthreads();
#pragma unroll
    for (int ks = 0; ks < 4; ++ks) {   // K=16 per step
      const int chunk = ks * 2 + lh;
      s16x8 af[2], bf[2];
#pragma unroll
      for (int mi = 0; mi < 2; ++mi) {
        const int ra = wr * 64 + mi * 32 + l31;
        af[mi] = *(const s16x8*)(As + ra * 64 + ((chunk ^ (ra & 7)) << 3));
      }
#pragma unroll
      for (int ni = 0; ni < 2; ++ni) {
        const int rb = wc * 64 + ni * 32 + l31;
        bf[ni] = *(const s16x8*)(Bs + rb * 64 + ((chunk ^ (rb & 7)) << 3));
      }
#pragma unroll
      for (int mi = 0; mi < 2; ++mi)
#pragma unroll
        for (int ni = 0; ni < 2; ++ni)
          acc[mi][ni] = __builtin_amdgcn_mfma_f32_32x32x16_bf16(af[mi], bf[ni], acc[mi][ni], 0, 0, 0);
    }
  }

#pragma unroll
  for (int mi = 0; mi < 2; ++mi)
#pragma unroll
    for (int ni = 0; ni < 2; ++ni) {
      const int col = n0 + wc * 64 + ni * 32 + l31;
#pragma unroll
      for (int reg = 0; reg < 16; ++reg) {
        const int row = m0 + wr * 64 + mi * 32 + 4 * lh + (reg & 3) + 8 * (reg >> 2);
        const float v = acc[mi][ni][reg];
        if constexpr (sizeof(OT) == 2) {
          C[(size_t)row * N + col] = (OT)f2bf(v);
        } else {
          C[(size_t)row * N + col] = v;
        }
      }
    }
}

// ---------------- merged Q+K GEMM (32x32x16, BK=64) ----------------
// grid dim(32,32) = 1024 blocks: bx<16 computes Q tile, bx>=16 computes K tile.
__global__ __launch_bounds__(256) void gemm_qk(const u16* __restrict__ A,
                                               const u16* __restrict__ B0,
                                               const u16* __restrict__ B1,
                                               u16* __restrict__ C0,
                                               u16* __restrict__ C1) {
  constexpr int K = 2048, N = 2048;
  __shared__ __align__(16) u16 As[128 * 64];
  __shared__ __align__(16) u16 Bs[128 * 64];
  const int bx = blockIdx.x;
  const u16* B = (bx >> 4) ? B1 : B0;
  u16* C = (bx >> 4) ? C1 : C0;
  const int n0 = (bx & 15) * 128, m0 = blockIdx.y * 128;
  const int t  = threadIdx.x;
  const int w  = t >> 6, l = t & 63;
  const int l31 = l & 31, lh = l >> 5;
  const int wr = w >> 1, wc = w & 1;

  f32x16 acc[2][2];
#pragma unroll
  for (int mi = 0; mi < 2; ++mi)
#pragma unroll
    for (int ni = 0; ni < 2; ++ni)
#pragma unroll
      for (int e = 0; e < 16; ++e) acc[mi][ni][e] = 0.f;

  for (int k0 = 0; k0 < K; k0 += 64) {
    __syncthreads();
#pragma unroll
    for (int i = 0; i < 4; ++i) {
      const int ci = i * 256 + t;
      const int r = ci >> 3, c = ci & 7, gq = c ^ (r & 7);
      gll16(A + (size_t)(m0 + r) * K + k0 + gq * 8, As + ci * 8);
    }
#pragma unroll
    for (int i = 0; i < 4; ++i) {
      const int ci = i * 256 + t;
      const int r = ci >> 3, c = ci & 7, gq = c ^ (r & 7);
      gll16(B + (size_t)(n0 + r) * K + k0 + gq * 8, Bs + ci * 8);
    }
    __syncthreads();
#pragma unroll
    for (int ks = 0; ks < 4; ++ks) {
      const int chunk = ks * 2 + lh;
      s16x8 af[2], bf[2];
#pragma unroll
      for (int mi = 0; mi < 2; ++mi) {
        const int ra = wr * 64 + mi * 32 + l31;
        af[mi] = *(const s16x8*)(As + ra * 64 + ((chunk ^ (ra & 7)) << 3));
      }
#pragma unroll
      for (int ni = 0; ni < 2; ++ni) {
        const int rb = wc * 64 + ni * 32 + l31;
        bf[ni] = *(const s16x8*)(Bs + rb * 64 + ((chunk ^ (rb & 7)) << 3));
      }
#pragma unroll
      for (int mi = 0; mi < 2; ++mi)
#pragma unroll
        for (int ni = 0; ni < 2; ++ni)
          acc[mi][ni] = __builtin_amdgcn_mfma_f32_32x32x16_bf16(af[mi], bf[ni], acc[mi][ni], 0, 0, 0);
    }
  }

#pragma unroll
  for (int mi = 0; mi < 2; ++mi)
#pragma unroll
    for (int ni = 0; ni < 2; ++ni) {
      const int col = n0 + wc * 64 + ni * 32 + l31;
#pragma unroll
      for (int reg = 0; reg < 16; ++reg) {
        const int row = m0 + wr * 64 + mi * 32 + 4 * lh + (reg & 3) + 8 * (reg >> 2);
        C[(size_t)row * N + col] = f2bf(acc[mi][ni][reg]);
      }
    }
}

// ---------------- RoPE (interleaved) on q and k, in place, bf16 ----------------
// Q is additionally pre-scaled by rsqrt(128)*log2(e): scores arrive in exp2 domain.
__global__ __launch_bounds__(256) void rope_kernel(u16* __restrict__ q, u16* __restrict__ k) {
  const float QS = 0.08838834764831845f * 1.4426950408889634f;
  const size_t t = (size_t)blockIdx.x * 256 + threadIdx.x;
  const size_t e8 = t * 8;
  const int col = (int)(e8 & (E_DIM - 1));
  const int row = (int)(e8 >> 11);
  const int s   = row & (SEQ - 1);
  const int d   = col & (HD - 1);
  float cs[4], sn[4];
#pragma unroll
  for (int j = 0; j < 4; ++j) {
    const float inv = exp2f(-0.20762050593046014f * (float)((d >> 1) + j));
    const float ang = (float)s * inv;
    sincosf(ang, &sn[j], &cs[j]);
  }
  u16* qp = q + e8;
  u16* kp = k + e8;
  union { u16 u[8]; i32x4 v; } a, b;
  a.v = *(const i32x4*)qp;
  b.v = *(const i32x4*)kp;
#pragma unroll
  for (int j = 0; j < 4; ++j) {
    const float csq = cs[j] * QS, snq = sn[j] * QS;
    const float q1 = bf2f(a.u[2 * j]), q2 = bf2f(a.u[2 * j + 1]);
    const float k1 = bf2f(b.u[2 * j]), k2 = bf2f(b.u[2 * j + 1]);
    a.u[2 * j]     = f2bf(q1 * csq - q2 * snq);
    a.u[2 * j + 1] = f2bf(q1 * snq + q2 * csq);
    b.u[2 * j]     = f2bf(k1 * cs[j] - k2 * sn[j]);
    b.u[2 * j + 1] = f2bf(k1 * sn[j] + k2 * cs[j]);
  }
  *(i32x4*)qp = a.v;
  *(i32x4*)kp = b.v;
}

// ---------------- causal flash attention v7: v6 structure, spill-free bound ----
// QBLK=128 (8 waves x 16 q-rows), KVBLK=64, double-buffered. LDS 64 KiB =
// 2 x (K 16K | V 16K) -> LDS permits 2 blocks/CU.
// __launch_bounds__(512, 2): on this toolchain the 2nd arg behaved as ~blocks/CU
// (round-2: arg=4 forced VGPR=64 -> scratch spill, FETCH 29->148MB, 222us).
// arg=2 caps VGPR at 128 >= the ~108 this kernel needs -> no spill, and
// VGPR<=128 allows 4 waves/SIMD -> true 2 blocks/CU residency. Independent
// co-resident blocks overlap each other's barrier/softmax-chain stalls.
// Paired q-tiles (15-j, j) -> uniform 34 tile-iters/block. Prefetch next KV
// tile + s_waitcnt vmcnt(4) (never 0 mid-loop) + raw s_barrier. P (16x64/wave,
// 2KB) overlays dead K region of the current buffer (8 waves x 2KB = 16KB).
// Diag masking on the last TWO tiles. XCD-grouped decode: all 16 j-blocks of
// one (b,h) share bx%8 -> same XCD L2.
__global__ __launch_bounds__(512, 2) void flash_kernel(const u16* __restrict__ q,
                                                       const u16* __restrict__ kmat,
                                                       const u16* __restrict__ vt,
                                                       u16* __restrict__ attn) {
  __shared__ __align__(16) u16 KV[32768];  // 64 KiB: buf0 K|V, buf1 K|V
  const int bx = blockIdx.x;
  const int j  = bx >> 5;                        // 0..15 paired-tile index
  const int bh = (bx & 7) * 4 + ((bx >> 3) & 3); // 0..31, constant bx%8 per (b,h)
  const int b  = bh >> 4, h = bh & 15;
  const int t = threadIdx.x, w = t >> 6, l = t & 63, lq = l >> 4, lm = l & 15;

  const u16* kbase = kmat + (size_t)(b * SEQ) * E_DIM + h * HD;
  const u16* vbase = vt + (size_t)(h * HD) * BS_TOT + (size_t)b * SEQ;
  const f32x4 fzero = {0.f, 0.f, 0.f, 0.f};

  auto stage = [&](int it) {
    const int base = (it & 1) << 14;  // buffer select (u16 units, 16384 apart)
    const int k0 = it * 64;
#pragma unroll
    for (int i = 0; i < 2; ++i) {     // K tile: 64(s) x 128(d) bf16 = 16 KB
      const int ci = i * 512 + t;
      const int r = ci >> 4, gq = (ci & 15) ^ (r & 15);
      gll16(kbase + (size_t)(k0 + r) * E_DIM + gq * 8, KV + base + ci * 8);
    }
#pragma unroll
    for (int i = 0; i < 2; ++i) {     // V^T tile: 128(d) x 64(s) bf16 = 16 KB
      const int ci = i * 512 + t;
      const int r = ci >> 3, gq = (ci & 7) ^ (r & 7);
      gll16(vbase + (size_t)r * BS_TOT + k0 + gq * 8, KV + base + 8192 + ci * 8);
    }
  };

  for (int pass = 0; pass < 2; ++pass) {
    const int qt = pass ? j : (15 - j);
    const int q0 = qt * 128;
    const int nT = 2 * qt + 2;

    stage(0);  // prologue: tile 0 into buf0 (pass 1: after end-of-loop barrier)

    const u16* qp = q + (size_t)(b * SEQ + q0 + w * 16) * E_DIM + h * HD;
    s16x8 qf[4];
#pragma unroll
    for (int kx = 0; kx < 4; ++kx)
      qf[kx] = *(const s16x8*)(qp + (size_t)lm * E_DIM + kx * 32 + lq * 8);

    float m_i[4], l_i[4];
    f32x4 acc_o[8];
#pragma unroll
    for (int rr = 0; rr < 4; ++rr) { m_i[rr] = -1e30f; l_i[rr] = 0.f; }
#pragma unroll
    for (int nd = 0; nd < 8; ++nd) acc_o[nd] = fzero;

    for (int it = 0; it < nT; ++it) {
      const int base = (it & 1) << 14;
      const int k0 = it * 64;
      // prefetch next tile; wait only for OWN tile's 4 loads (counted vmcnt)
      if (it + 1 < nT) {
        stage(it + 1);
        asm volatile("s_waitcnt vmcnt(4)" ::: "memory");
      } else {
        asm volatile("s_waitcnt vmcnt(0)" ::: "memory");
      }
      asm volatile("s_barrier" ::: "memory");  // (a) buf[it&1] staged block-wide

      // S = Q K^T  (per wave: 16 x 64), scores pre-scaled into exp2 domain
      f32x4 sc[4];
#pragma unroll
      for (int ni = 0; ni < 4; ++ni) sc[ni] = fzero;
      __builtin_amdgcn_s_setprio(1);
#pragma unroll
      for (int kx = 0; kx < 4; ++kx) {
        s16x8 kf[4];
#pragma unroll
        for (int ni = 0; ni < 4; ++ni) {
          const int rn = ni * 16 + lm;
          kf[ni] = *(const s16x8*)(KV + base + rn * 128 + (((kx * 4 + lq) ^ lm) << 3));
        }
#pragma unroll
        for (int ni = 0; ni < 4; ++ni)
          sc[ni] = __builtin_amdgcn_mfma_f32_16x16x32_bf16(qf[kx], kf[ni], sc[ni], 0, 0, 0);
      }
      __builtin_amdgcn_s_setprio(0);

      // online softmax (exp2 domain); last TWO tiles need diag masking
      const bool diag = (it >= nT - 2);
#pragma unroll
      for (int rr = 0; rr < 4; ++rr) {
        const int qrow = q0 + w * 16 + lq * 4 + rr;
        float mt = -1e30f;
#pragma unroll
        for (int ni = 0; ni < 4; ++ni) {
          float s = sc[ni][rr];
          if (diag && (k0 + ni * 16 + lm) > qrow) s = -1e30f;
          sc[ni][rr] = s;
          mt = fmaxf(mt, s);
        }
        mt = rmax16(mt);
        const float mn = fmaxf(m_i[rr], mt);
        const float al = exp2f(m_i[rr] - mn);
        float rs = 0.f;
#pragma unroll
        for (int ni = 0; ni < 4; ++ni) {
          const float p = exp2f(sc[ni][rr] - mn);
          sc[ni][rr] = p;
          rs += p;
        }
        rs = rsum16(rs);
        l_i[rr] = l_i[rr] * al + rs;
        m_i[rr] = mn;
#pragma unroll
        for (int nd = 0; nd < 8; ++nd) acc_o[nd][rr] *= al;
      }

      asm volatile("s_barrier" ::: "memory");  // (b) all waves' K reads retired
      u16* P = KV + base + w * 1024;           // overlay dead K region, per wave
#pragma unroll
      for (int rr = 0; rr < 4; ++rr) {
        const int r = lq * 4 + rr;
#pragma unroll
        for (int ni = 0; ni < 4; ++ni) {
          const int c = ni * 16 + lm;
          P[r * 64 + (((c >> 3) ^ (r & 7)) << 3) + (c & 7)] = f2bf(sc[ni][rr]);
        }
      }

      // O += P V  (own-wave P slice: lgkmcnt ordering, no extra barrier)
      __builtin_amdgcn_s_setprio(1);
#pragma unroll
      for (int kx = 0; kx < 2; ++kx) {
        const s16x8 pf = *(const s16x8*)(P + lm * 64 + (((kx * 4 + lq) ^ (lm & 7)) << 3));
#pragma unroll
        for (int nd = 0; nd < 8; ++nd) {
          const int rn = nd * 16 + lm;
          const s16x8 vf = *(const s16x8*)(KV + base + 8192 + rn * 64 + (((kx * 4 + lq) ^ (lm & 7)) << 3));
          acc_o[nd] = __builtin_amdgcn_mfma_f32_16x16x32_bf16(pf, vf, acc_o[nd], 0, 0, 0);
        }
      }
      __builtin_amdgcn_s_setprio(0);

      asm volatile("s_barrier" ::: "memory");  // (c) buf consumed; next stage safe
    }

    // epilogue for this pass: normalize and store bf16
    u16* op = attn + (size_t)(b * SEQ + q0 + w * 16) * E_DIM + h * HD;
#pragma unroll
    for (int rr = 0; rr < 4; ++rr) {
      const float inv = 1.0f / l_i[rr];
      const int row = lq * 4 + rr;
#pragma unroll
      for (int nd = 0; nd < 8; ++nd) {
        const int colc = nd * 16 + lm;
        op[(size_t)row * E_DIM + colc] = f2bf(acc_o[nd][rr] * inv);
      }
    }
  }
}

// ---------------- launch ----------------
// ws 32 MiB: xb @0 (16M, reused as attn), vslot @16M (16M): Wq_bf+Wk_bf copies,
// then V^T (overwrites them), then Wo_bf. d_out scratch: qb @0, kb @+16M.
extern "C" void kernel_launch(void* const* d_in, const int* in_sizes, int n_in,
                              void* d_out, int out_size, void* d_ws, size_t ws_size,
                              hipStream_t stream) {
  const float* x  = (const float*)d_in[0];
  const float* Wq = (const float*)d_in[1];
  const float* Wk = (const float*)d_in[2];
  const float* Wv = (const float*)d_in[3];
  const float* Wo = (const float*)d_in[4];
  float* out = (float*)d_out;
  char* ws = (char*)d_ws;

  u16* xb    = (u16*)(ws);                         // 16 MiB
  u16* vslot = (u16*)(ws + (size_t)16 * 1048576);  // 16 MiB
  u16* wq_bf = vslot;                              // 8 MiB (dead after gemm_qk)
  u16* wk_bf = vslot + (size_t)4 * 1048576;        // 8 MiB (dead after gemm_qk)
  u16* vtb   = vslot;                              // V^T [E][B*S]
  u16* wo_bf = vslot;                              // Wo bf16 (after flash)
  u16* qb    = (u16*)d_out;                        // 16 MiB scratch in d_out
  u16* kb    = (u16*)d_out + (size_t)8 * 1048576;  // 16 MiB scratch in d_out
  u16* attnb = xb;

  (void)in_sizes; (void)n_in; (void)out_size; (void)ws_size;

  cast_kernel<<<4096, 256, 0, stream>>>(x, xb);
  cast2_kernel<<<4096, 256, 0, stream>>>(Wq, wq_bf, Wk, wk_bf, 2048);
  gemm_qk<<<dim3(32, 32), 256, 0, stream>>>(xb, wq_bf, wk_bf, qb, kb);
  // V^T[e][s] = Wv[e][:] . x[s][:]  (A = Wv fp32 converted on stage, B = xb)
  gemm_nt<u16, true><<<dim3(32, 16), 256, 0, stream>>>(Wv, xb, vtb, 2048, 4096, 2048);
  rope_kernel<<<4096, 256, 0, stream>>>(qb, kb);
  flash_kernel<<<512, 512, 0, stream>>>(qb, kb, vtb, attnb);
  cast_kernel<<<2048, 256, 0, stream>>>(Wo, wo_bf);
  gemm_nt<float, false><<<dim3(16, 32), 256, 0, stream>>>(attnb, wo_bf, out, 4096, 2048, 2048);
}

// Round 4
// 420.470 us; speedup vs baseline: 1.2770x; 1.2369x over previous
//
#include <hip/hip_runtime.h>
#include <cstdint>
#include <cmath>

typedef short s16x8 __attribute__((ext_vector_type(8)));
typedef float f32x4 __attribute__((ext_vector_type(4)));
typedef float f32x16 __attribute__((ext_vector_type(16)));
typedef int   i32x4 __attribute__((ext_vector_type(4)));
typedef unsigned short u16;

#define E_DIM 2048
#define SEQ   2048
#define NB    2
#define NH    16
#define HD    128
#define BS_TOT 4096   // NB*SEQ

__device__ __forceinline__ u16 f2bf(float f) {
  unsigned u = __float_as_uint(f);
  u += 0x7fffu + ((u >> 16) & 1u);
  return (u16)(u >> 16);
}
__device__ __forceinline__ float bf2f(u16 h) {
  return __uint_as_float(((unsigned)h) << 16);
}
__device__ __forceinline__ float rmax16(float v) {
  v = fmaxf(v, __shfl_xor(v, 1));
  v = fmaxf(v, __shfl_xor(v, 2));
  v = fmaxf(v, __shfl_xor(v, 4));
  v = fmaxf(v, __shfl_xor(v, 8));
  return v;
}
__device__ __forceinline__ float rsum16(float v) {
  v += __shfl_xor(v, 1);
  v += __shfl_xor(v, 2);
  v += __shfl_xor(v, 4);
  v += __shfl_xor(v, 8);
  return v;
}

// async global->LDS, 16B per lane. LDS dest is wave-uniform base + lane*16;
// swizzle goes into the GLOBAL pointer.
__device__ __forceinline__ void gll16(const u16* g, u16* l) {
  __builtin_amdgcn_global_load_lds(
      (const __attribute__((address_space(1))) void*)g,
      (__attribute__((address_space(3))) void*)l, 16, 0, 0);
}

// ---------------- cast fp32 -> bf16, 8 elements/thread ----------------
__global__ __launch_bounds__(256) void cast_kernel(const float* __restrict__ in,
                                                   u16* __restrict__ out) {
  const size_t t = (size_t)blockIdx.x * 256 + threadIdx.x;
  const float* p = in + t * 8;
  f32x4 a = *(const f32x4*)p;
  f32x4 b = *(const f32x4*)(p + 4);
  union { u16 u[8]; i32x4 v; } r;
  r.u[0] = f2bf(a[0]); r.u[1] = f2bf(a[1]); r.u[2] = f2bf(a[2]); r.u[3] = f2bf(a[3]);
  r.u[4] = f2bf(b[0]); r.u[5] = f2bf(b[1]); r.u[6] = f2bf(b[2]); r.u[7] = f2bf(b[3]);
  *(i32x4*)(out + t * 8) = r.v;
}

// two-array cast in one dispatch (blocks [0,half) -> 0, [half,2*half) -> 1)
__global__ __launch_bounds__(256) void cast2_kernel(const float* __restrict__ in0,
                                                    u16* __restrict__ out0,
                                                    const float* __restrict__ in1,
                                                    u16* __restrict__ out1,
                                                    int half) {
  const int bsel = blockIdx.x >= half;
  const float* in = bsel ? in1 : in0;
  u16* out = bsel ? out1 : out0;
  const size_t t = (size_t)(blockIdx.x - (bsel ? half : 0)) * 256 + threadIdx.x;
  const float* p = in + t * 8;
  f32x4 a = *(const f32x4*)p;
  f32x4 b = *(const f32x4*)(p + 4);
  union { u16 u[8]; i32x4 v; } r;
  r.u[0] = f2bf(a[0]); r.u[1] = f2bf(a[1]); r.u[2] = f2bf(a[2]); r.u[3] = f2bf(a[3]);
  r.u[4] = f2bf(b[0]); r.u[5] = f2bf(b[1]); r.u[6] = f2bf(b[2]); r.u[7] = f2bf(b[3]);
  *(i32x4*)(out + t * 8) = r.v;
}

// ---------------- NT GEMM: C[M,N] = A[M,K] * B[N,K]^T  (32x32x16 MFMA) -------
// 128x128 tile, BK=64, global_load_lds 16B staging, chunk swizzle via global
// pointer (gq = c ^ (r&7)). Wave tile 64x64 = 2x2 of 32x32x16.
// A/B frag: m|n = lane&31, k = (lane>>5)*8+j; C/D: col=lane&31,
// row = (reg&3)+8*(reg>>2)+4*(lane>>5)  [m74/m101-verified].
// CVTA: A is fp32 converted during VGPR staging (Wv GEMM only).
template <typename OT, bool CVTA>
__global__ __launch_bounds__(256) void gemm_nt(const void* __restrict__ Av,
                                               const u16* __restrict__ B,
                                               OT* __restrict__ C,
                                               int M, int N, int K) {
  __shared__ __align__(16) u16 As[128 * 64];
  __shared__ __align__(16) u16 Bs[128 * 64];
  const int t  = threadIdx.x;
  const int w  = t >> 6, l = t & 63;
  const int l31 = l & 31, lh = l >> 5;
  const int wr = w >> 1, wc = w & 1;
  const int m0 = blockIdx.y * 128, n0 = blockIdx.x * 128;

  f32x16 acc[2][2];
#pragma unroll
  for (int mi = 0; mi < 2; ++mi)
#pragma unroll
    for (int ni = 0; ni < 2; ++ni)
#pragma unroll
      for (int e = 0; e < 16; ++e) acc[mi][ni][e] = 0.f;

  for (int k0 = 0; k0 < K; k0 += 64) {
    __syncthreads();
    if constexpr (CVTA) {
      const float* A = (const float*)Av;
#pragma unroll
      for (int i = 0; i < 4; ++i) {
        const int ci = i * 256 + t;
        const int r = ci >> 3, c = ci & 7, gq = c ^ (r & 7);
        const float* s = A + (size_t)(m0 + r) * K + k0 + gq * 8;
        f32x4 a = *(const f32x4*)s;
        f32x4 b = *(const f32x4*)(s + 4);
        union { u16 u[8]; i32x4 v; } rr;
        rr.u[0] = f2bf(a[0]); rr.u[1] = f2bf(a[1]); rr.u[2] = f2bf(a[2]); rr.u[3] = f2bf(a[3]);
        rr.u[4] = f2bf(b[0]); rr.u[5] = f2bf(b[1]); rr.u[6] = f2bf(b[2]); rr.u[7] = f2bf(b[3]);
        *(i32x4*)(As + ci * 8) = rr.v;
      }
    } else {
      const u16* A = (const u16*)Av;
#pragma unroll
      for (int i = 0; i < 4; ++i) {
        const int ci = i * 256 + t;
        const int r = ci >> 3, c = ci & 7, gq = c ^ (r & 7);
        gll16(A + (size_t)(m0 + r) * K + k0 + gq * 8, As + ci * 8);
      }
    }
#pragma unroll
    for (int i = 0; i < 4; ++i) {
      const int ci = i * 256 + t;
      const int r = ci >> 3, c = ci & 7, gq = c ^ (r & 7);
      gll16(B + (size_t)(n0 + r) * K + k0 + gq * 8, Bs + ci * 8);
    }
    __syncthreads();
#pragma unroll
    for (int ks = 0; ks < 4; ++ks) {   // K=16 per step
      const int chunk = ks * 2 + lh;
      s16x8 af[2], bf[2];
#pragma unroll
      for (int mi = 0; mi < 2; ++mi) {
        const int ra = wr * 64 + mi * 32 + l31;
        af[mi] = *(const s16x8*)(As + ra * 64 + ((chunk ^ (ra & 7)) << 3));
      }
#pragma unroll
      for (int ni = 0; ni < 2; ++ni) {
        const int rb = wc * 64 + ni * 32 + l31;
        bf[ni] = *(const s16x8*)(Bs + rb * 64 + ((chunk ^ (rb & 7)) << 3));
      }
#pragma unroll
      for (int mi = 0; mi < 2; ++mi)
#pragma unroll
        for (int ni = 0; ni < 2; ++ni)
          acc[mi][ni] = __builtin_amdgcn_mfma_f32_32x32x16_bf16(af[mi], bf[ni], acc[mi][ni], 0, 0, 0);
    }
  }

#pragma unroll
  for (int mi = 0; mi < 2; ++mi)
#pragma unroll
    for (int ni = 0; ni < 2; ++ni) {
      const int col = n0 + wc * 64 + ni * 32 + l31;
#pragma unroll
      for (int reg = 0; reg < 16; ++reg) {
        const int row = m0 + wr * 64 + mi * 32 + 4 * lh + (reg & 3) + 8 * (reg >> 2);
        const float v = acc[mi][ni][reg];
        if constexpr (sizeof(OT) == 2) {
          C[(size_t)row * N + col] = (OT)f2bf(v);
        } else {
          C[(size_t)row * N + col] = v;
        }
      }
    }
}

// ---------------- merged Q+K GEMM (32x32x16, BK=64) ----------------
// grid dim(32,32) = 1024 blocks: bx<16 computes Q tile, bx>=16 computes K tile.
__global__ __launch_bounds__(256) void gemm_qk(const u16* __restrict__ A,
                                               const u16* __restrict__ B0,
                                               const u16* __restrict__ B1,
                                               u16* __restrict__ C0,
                                               u16* __restrict__ C1) {
  constexpr int K = 2048, N = 2048;
  __shared__ __align__(16) u16 As[128 * 64];
  __shared__ __align__(16) u16 Bs[128 * 64];
  const int bx = blockIdx.x;
  const u16* B = (bx >> 4) ? B1 : B0;
  u16* C = (bx >> 4) ? C1 : C0;
  const int n0 = (bx & 15) * 128, m0 = blockIdx.y * 128;
  const int t  = threadIdx.x;
  const int w  = t >> 6, l = t & 63;
  const int l31 = l & 31, lh = l >> 5;
  const int wr = w >> 1, wc = w & 1;

  f32x16 acc[2][2];
#pragma unroll
  for (int mi = 0; mi < 2; ++mi)
#pragma unroll
    for (int ni = 0; ni < 2; ++ni)
#pragma unroll
      for (int e = 0; e < 16; ++e) acc[mi][ni][e] = 0.f;

  for (int k0 = 0; k0 < K; k0 += 64) {
    __syncthreads();
#pragma unroll
    for (int i = 0; i < 4; ++i) {
      const int ci = i * 256 + t;
      const int r = ci >> 3, c = ci & 7, gq = c ^ (r & 7);
      gll16(A + (size_t)(m0 + r) * K + k0 + gq * 8, As + ci * 8);
    }
#pragma unroll
    for (int i = 0; i < 4; ++i) {
      const int ci = i * 256 + t;
      const int r = ci >> 3, c = ci & 7, gq = c ^ (r & 7);
      gll16(B + (size_t)(n0 + r) * K + k0 + gq * 8, Bs + ci * 8);
    }
    __syncthreads();
#pragma unroll
    for (int ks = 0; ks < 4; ++ks) {
      const int chunk = ks * 2 + lh;
      s16x8 af[2], bf[2];
#pragma unroll
      for (int mi = 0; mi < 2; ++mi) {
        const int ra = wr * 64 + mi * 32 + l31;
        af[mi] = *(const s16x8*)(As + ra * 64 + ((chunk ^ (ra & 7)) << 3));
      }
#pragma unroll
      for (int ni = 0; ni < 2; ++ni) {
        const int rb = wc * 64 + ni * 32 + l31;
        bf[ni] = *(const s16x8*)(Bs + rb * 64 + ((chunk ^ (rb & 7)) << 3));
      }
#pragma unroll
      for (int mi = 0; mi < 2; ++mi)
#pragma unroll
        for (int ni = 0; ni < 2; ++ni)
          acc[mi][ni] = __builtin_amdgcn_mfma_f32_32x32x16_bf16(af[mi], bf[ni], acc[mi][ni], 0, 0, 0);
    }
  }

#pragma unroll
  for (int mi = 0; mi < 2; ++mi)
#pragma unroll
    for (int ni = 0; ni < 2; ++ni) {
      const int col = n0 + wc * 64 + ni * 32 + l31;
#pragma unroll
      for (int reg = 0; reg < 16; ++reg) {
        const int row = m0 + wr * 64 + mi * 32 + 4 * lh + (reg & 3) + 8 * (reg >> 2);
        C[(size_t)row * N + col] = f2bf(acc[mi][ni][reg]);
      }
    }
}

// ---------------- RoPE (interleaved) on q and k, in place, bf16 ----------------
// Q is additionally pre-scaled by rsqrt(128)*log2(e): scores arrive in exp2 domain.
__global__ __launch_bounds__(256) void rope_kernel(u16* __restrict__ q, u16* __restrict__ k) {
  const float QS = 0.08838834764831845f * 1.4426950408889634f;
  const size_t t = (size_t)blockIdx.x * 256 + threadIdx.x;
  const size_t e8 = t * 8;
  const int col = (int)(e8 & (E_DIM - 1));
  const int row = (int)(e8 >> 11);
  const int s   = row & (SEQ - 1);
  const int d   = col & (HD - 1);
  float cs[4], sn[4];
#pragma unroll
  for (int j = 0; j < 4; ++j) {
    const float inv = exp2f(-0.20762050593046014f * (float)((d >> 1) + j));
    const float ang = (float)s * inv;
    sincosf(ang, &sn[j], &cs[j]);
  }
  u16* qp = q + e8;
  u16* kp = k + e8;
  union { u16 u[8]; i32x4 v; } a, b;
  a.v = *(const i32x4*)qp;
  b.v = *(const i32x4*)kp;
#pragma unroll
  for (int j = 0; j < 4; ++j) {
    const float csq = cs[j] * QS, snq = sn[j] * QS;
    const float q1 = bf2f(a.u[2 * j]), q2 = bf2f(a.u[2 * j + 1]);
    const float k1 = bf2f(b.u[2 * j]), k2 = bf2f(b.u[2 * j + 1]);
    a.u[2 * j]     = f2bf(q1 * csq - q2 * snq);
    a.u[2 * j + 1] = f2bf(q1 * snq + q2 * csq);
    b.u[2 * j]     = f2bf(k1 * cs[j] - k2 * sn[j]);
    b.u[2 * j + 1] = f2bf(k1 * sn[j] + k2 * cs[j]);
  }
  *(i32x4*)qp = a.v;
  *(i32x4*)kp = b.v;
}

// ---------------- causal flash attention v8 ----------------
// v5 structure restored (KVBLK=128, QBLK=128, grid 256, 17 uniform iters via
// pair (15-j, j), j=0..7 -- each q-tile exactly once; v6/v7's grid-512 j=0..15
// computed every tile TWICE, WRITE_SIZE 31MB = 2x output proved it).
// Changes vs v5:
//  * P gets a DEDICATED 16 KiB LDS region (16x64 u16/wave, PV in two k-halves)
//    -> (1) removes v5's latent race (P overlaid buf0's K region even while
//    stage(it+1) DMA'd into it on odd iters); (2) deletes barrier (b): P is
//    own-wave RW in its own region -> 2 barriers/iter instead of 3, softmax
//    tail no longer block-syncs before P writes.
//  * LDS total 144 KiB (KV 2x(16K K|16K V u16) + P 8x1024 u16) <= 160 KiB.
// Prefetch next KV tile + s_waitcnt vmcnt(8) (never 0 mid-loop) + raw
// s_barrier. Diag masking last tile only. XCD-grouped decode: all 8 j-blocks
// of one (b,h) share bx%8 -> same XCD L2.
__global__ __launch_bounds__(512, 2) void flash_kernel(const u16* __restrict__ q,
                                                       const u16* __restrict__ kmat,
                                                       const u16* __restrict__ vt,
                                                       u16* __restrict__ attn) {
  __shared__ __align__(16) u16 KV[73728];  // 144 KiB: buf0 K|V, buf1 K|V, P
  const int bx = blockIdx.x;
  const int j  = bx >> 5;                        // 0..7  paired-tile index
  const int bh = (bx & 7) * 4 + ((bx >> 3) & 3); // 0..31, constant bx%8 per (b,h)
  const int b  = bh >> 4, h = bh & 15;
  const int t = threadIdx.x, w = t >> 6, l = t & 63, lq = l >> 4, lm = l & 15;

  u16* Pw = KV + 65536 + w * 1024;  // dedicated per-wave 16x64 P slice
  const u16* kbase = kmat + (size_t)(b * SEQ) * E_DIM + h * HD;
  const u16* vbase = vt + (size_t)(h * HD) * BS_TOT + (size_t)b * SEQ;
  const f32x4 fzero = {0.f, 0.f, 0.f, 0.f};

  auto stage = [&](int it) {
    const int base = (it & 1) << 15;  // buffer select (u16 units, 32768 apart)
    const int k0 = it * 128;
#pragma unroll
    for (int i = 0; i < 4; ++i) {     // K tile: 128(s) x 128(d) bf16 = 32 KB
      const int ci = i * 512 + t;
      const int r = ci >> 4, gq = (ci & 15) ^ (r & 15);
      gll16(kbase + (size_t)(k0 + r) * E_DIM + gq * 8, KV + base + ci * 8);
    }
#pragma unroll
    for (int i = 0; i < 4; ++i) {     // V^T tile: 128(d) x 128(s) bf16 = 32 KB
      const int ci = i * 512 + t;
      const int r = ci >> 4, gq = (ci & 15) ^ (r & 15);
      gll16(vbase + (size_t)r * BS_TOT + k0 + gq * 8, KV + base + 16384 + ci * 8);
    }
  };

  for (int pass = 0; pass < 2; ++pass) {
    const int qt = pass ? j : (15 - j);
    const int q0 = qt * 128;
    const int nT = qt + 1;

    stage(0);  // prologue: tile 0 into buf0 (pass 1: after end-of-loop barrier)

    const u16* qp = q + (size_t)(b * SEQ + q0 + w * 16) * E_DIM + h * HD;
    s16x8 qf[4];
#pragma unroll
    for (int kx = 0; kx < 4; ++kx)
      qf[kx] = *(const s16x8*)(qp + (size_t)lm * E_DIM + kx * 32 + lq * 8);

    float m_i[4], l_i[4];
    f32x4 acc_o[8];
#pragma unroll
    for (int rr = 0; rr < 4; ++rr) { m_i[rr] = -1e30f; l_i[rr] = 0.f; }
#pragma unroll
    for (int nd = 0; nd < 8; ++nd) acc_o[nd] = fzero;

    for (int it = 0; it < nT; ++it) {
      const int base = (it & 1) << 15;
      const int k0 = it * 128;
      // prefetch next tile; wait only for OWN tile's 8 loads (counted vmcnt)
      if (it + 1 < nT) {
        stage(it + 1);
        asm volatile("s_waitcnt vmcnt(8)" ::: "memory");
      } else {
        asm volatile("s_waitcnt vmcnt(0)" ::: "memory");
      }
      asm volatile("s_barrier" ::: "memory");  // (a) buf[it&1] staged block-wide

      // S = Q K^T  (per wave: 16 x 128), scores pre-scaled into exp2 domain
      f32x4 sc[8];
#pragma unroll
      for (int ni = 0; ni < 8; ++ni) sc[ni] = fzero;
      __builtin_amdgcn_s_setprio(1);
#pragma unroll
      for (int kx = 0; kx < 4; ++kx) {
        s16x8 kf[8];
#pragma unroll
        for (int ni = 0; ni < 8; ++ni) {
          const int rn = ni * 16 + lm;
          kf[ni] = *(const s16x8*)(KV + base + rn * 128 + (((kx * 4 + lq) ^ lm) << 3));
        }
#pragma unroll
        for (int ni = 0; ni < 8; ++ni)
          sc[ni] = __builtin_amdgcn_mfma_f32_16x16x32_bf16(qf[kx], kf[ni], sc[ni], 0, 0, 0);
      }
      __builtin_amdgcn_s_setprio(0);

      // online softmax (exp2 domain); diag masking on the last tile only
      const bool diag = (it == nT - 1);
#pragma unroll
      for (int rr = 0; rr < 4; ++rr) {
        const int qrow = q0 + w * 16 + lq * 4 + rr;
        float mt = -1e30f;
#pragma unroll
        for (int ni = 0; ni < 8; ++ni) {
          float s = sc[ni][rr];
          if (diag && (k0 + ni * 16 + lm) > qrow) s = -1e30f;
          sc[ni][rr] = s;
          mt = fmaxf(mt, s);
        }
        mt = rmax16(mt);
        const float mn = fmaxf(m_i[rr], mt);
        const float al = exp2f(m_i[rr] - mn);
        float rs = 0.f;
#pragma unroll
        for (int ni = 0; ni < 8; ++ni) {
          const float p = exp2f(sc[ni][rr] - mn);
          sc[ni][rr] = p;
          rs += p;
        }
        rs = rsum16(rs);
        l_i[rr] = l_i[rr] * al + rs;
        m_i[rr] = mn;
#pragma unroll
        for (int nd = 0; nd < 8; ++nd) acc_o[nd][rr] *= al;
      }

      // O += P V in two k-halves through the dedicated per-wave P slice
      // (own-wave write->read, lgkmcnt-ordered; NO block barrier needed)
      __builtin_amdgcn_s_setprio(1);
#pragma unroll
      for (int half = 0; half < 2; ++half) {
#pragma unroll
        for (int rr = 0; rr < 4; ++rr) {
          const int r = lq * 4 + rr;
#pragma unroll
          for (int ni = 0; ni < 4; ++ni) {
            const int c = ni * 16 + lm;
            Pw[r * 64 + (((c >> 3) ^ (r & 7)) << 3) + (c & 7)] =
                f2bf(sc[half * 4 + ni][rr]);
          }
        }
#pragma unroll
        for (int kx = 0; kx < 2; ++kx) {
          const s16x8 pf = *(const s16x8*)(Pw + lm * 64 + (((kx * 4 + lq) ^ (lm & 7)) << 3));
#pragma unroll
          for (int nd = 0; nd < 8; ++nd) {
            const int rn = nd * 16 + lm;
            const s16x8 vf = *(const s16x8*)(KV + base + 16384 + rn * 128 +
                                             (((half * 8 + kx * 4 + lq) ^ lm) << 3));
            acc_o[nd] = __builtin_amdgcn_mfma_f32_16x16x32_bf16(pf, vf, acc_o[nd], 0, 0, 0);
          }
        }
      }
      __builtin_amdgcn_s_setprio(0);

      asm volatile("s_barrier" ::: "memory");  // (c) buf consumed; next stage safe
    }

    // epilogue for this pass: normalize and store bf16
    u16* op = attn + (size_t)(b * SEQ + q0 + w * 16) * E_DIM + h * HD;
#pragma unroll
    for (int rr = 0; rr < 4; ++rr) {
      const float inv = 1.0f / l_i[rr];
      const int row = lq * 4 + rr;
#pragma unroll
      for (int nd = 0; nd < 8; ++nd) {
        const int colc = nd * 16 + lm;
        op[(size_t)row * E_DIM + colc] = f2bf(acc_o[nd][rr] * inv);
      }
    }
  }
}

// ---------------- launch ----------------
// ws 32 MiB: xb @0 (16M, reused as attn), vslot @16M (16M): Wq_bf+Wk_bf copies,
// then V^T (overwrites them), then Wo_bf. d_out scratch: qb @0, kb @+16M.
extern "C" void kernel_launch(void* const* d_in, const int* in_sizes, int n_in,
                              void* d_out, int out_size, void* d_ws, size_t ws_size,
                              hipStream_t stream) {
  const float* x  = (const float*)d_in[0];
  const float* Wq = (const float*)d_in[1];
  const float* Wk = (const float*)d_in[2];
  const float* Wv = (const float*)d_in[3];
  const float* Wo = (const float*)d_in[4];
  float* out = (float*)d_out;
  char* ws = (char*)d_ws;

  u16* xb    = (u16*)(ws);                         // 16 MiB
  u16* vslot = (u16*)(ws + (size_t)16 * 1048576);  // 16 MiB
  u16* wq_bf = vslot;                              // 8 MiB (dead after gemm_qk)
  u16* wk_bf = vslot + (size_t)4 * 1048576;        // 8 MiB (dead after gemm_qk)
  u16* vtb   = vslot;                              // V^T [E][B*S]
  u16* wo_bf = vslot;                              // Wo bf16 (after flash)
  u16* qb    = (u16*)d_out;                        // 16 MiB scratch in d_out
  u16* kb    = (u16*)d_out + (size_t)8 * 1048576;  // 16 MiB scratch in d_out
  u16* attnb = xb;

  (void)in_sizes; (void)n_in; (void)out_size; (void)ws_size;

  cast_kernel<<<4096, 256, 0, stream>>>(x, xb);
  cast2_kernel<<<4096, 256, 0, stream>>>(Wq, wq_bf, Wk, wk_bf, 2048);
  gemm_qk<<<dim3(32, 32), 256, 0, stream>>>(xb, wq_bf, wk_bf, qb, kb);
  // V^T[e][s] = Wv[e][:] . x[s][:]  (A = Wv fp32 converted on stage, B = xb)
  gemm_nt<u16, true><<<dim3(32, 16), 256, 0, stream>>>(Wv, xb, vtb, 2048, 4096, 2048);
  rope_kernel<<<4096, 256, 0, stream>>>(qb, kb);
  flash_kernel<<<256, 512, 0, stream>>>(qb, kb, vtb, attnb);
  cast_kernel<<<2048, 256, 0, stream>>>(Wo, wo_bf);
  gemm_nt<float, false><<<dim3(16, 32), 256, 0, stream>>>(attnb, wo_bf, out, 4096, 2048, 2048);
}

// Round 5
// 404.748 us; speedup vs baseline: 1.3266x; 1.0388x over previous
//
#include <hip/hip_runtime.h>
#include <cstdint>
#include <cmath>

typedef short s16x8 __attribute__((ext_vector_type(8)));
typedef float f32x4 __attribute__((ext_vector_type(4)));
typedef float f32x16 __attribute__((ext_vector_type(16)));
typedef int   i32x4 __attribute__((ext_vector_type(4)));
typedef unsigned short u16;

#define E_DIM 2048
#define SEQ   2048
#define NB    2
#define NH    16
#define HD    128
#define BS_TOT 4096   // NB*SEQ

__device__ __forceinline__ u16 f2bf(float f) {
  unsigned u = __float_as_uint(f);
  u += 0x7fffu + ((u >> 16) & 1u);
  return (u16)(u >> 16);
}
__device__ __forceinline__ float bf2f(u16 h) {
  return __uint_as_float(((unsigned)h) << 16);
}
__device__ __forceinline__ float rmax16(float v) {
  v = fmaxf(v, __shfl_xor(v, 1));
  v = fmaxf(v, __shfl_xor(v, 2));
  v = fmaxf(v, __shfl_xor(v, 4));
  v = fmaxf(v, __shfl_xor(v, 8));
  return v;
}
__device__ __forceinline__ float rsum16(float v) {
  v += __shfl_xor(v, 1);
  v += __shfl_xor(v, 2);
  v += __shfl_xor(v, 4);
  v += __shfl_xor(v, 8);
  return v;
}

// async global->LDS, 16B per lane. LDS dest is wave-uniform base + lane*16;
// swizzle goes into the GLOBAL pointer.
__device__ __forceinline__ void gll16(const u16* g, u16* l) {
  __builtin_amdgcn_global_load_lds(
      (const __attribute__((address_space(1))) void*)g,
      (__attribute__((address_space(3))) void*)l, 16, 0, 0);
}

// ---------------- cast fp32 -> bf16, 8 elements/thread ----------------
__global__ __launch_bounds__(256) void cast_kernel(const float* __restrict__ in,
                                                   u16* __restrict__ out) {
  const size_t t = (size_t)blockIdx.x * 256 + threadIdx.x;
  const float* p = in + t * 8;
  f32x4 a = *(const f32x4*)p;
  f32x4 b = *(const f32x4*)(p + 4);
  union { u16 u[8]; i32x4 v; } r;
  r.u[0] = f2bf(a[0]); r.u[1] = f2bf(a[1]); r.u[2] = f2bf(a[2]); r.u[3] = f2bf(a[3]);
  r.u[4] = f2bf(b[0]); r.u[5] = f2bf(b[1]); r.u[6] = f2bf(b[2]); r.u[7] = f2bf(b[3]);
  *(i32x4*)(out + t * 8) = r.v;
}

// three-array cast in one dispatch: [0,n0) -> 0, [n0,n0+n1) -> 1, rest -> 2
__global__ __launch_bounds__(256) void cast3_kernel(const float* __restrict__ in0,
                                                    u16* __restrict__ out0,
                                                    const float* __restrict__ in1,
                                                    u16* __restrict__ out1,
                                                    const float* __restrict__ in2,
                                                    u16* __restrict__ out2,
                                                    int n0, int n1) {
  const int bx = blockIdx.x;
  const float* in; u16* out; int bb;
  if (bx < n0)           { in = in0; out = out0; bb = bx; }
  else if (bx < n0 + n1) { in = in1; out = out1; bb = bx - n0; }
  else                   { in = in2; out = out2; bb = bx - n0 - n1; }
  const size_t t = (size_t)bb * 256 + threadIdx.x;
  const float* p = in + t * 8;
  f32x4 a = *(const f32x4*)p;
  f32x4 b = *(const f32x4*)(p + 4);
  union { u16 u[8]; i32x4 v; } r;
  r.u[0] = f2bf(a[0]); r.u[1] = f2bf(a[1]); r.u[2] = f2bf(a[2]); r.u[3] = f2bf(a[3]);
  r.u[4] = f2bf(b[0]); r.u[5] = f2bf(b[1]); r.u[6] = f2bf(b[2]); r.u[7] = f2bf(b[3]);
  *(i32x4*)(out + t * 8) = r.v;
}

// ---------------- NT GEMM v2: double-buffered counted-vmcnt pipeline ---------
// C[M,N] = A[M,K] * B[N,K]^T, 128x128 tile, BK=64, 32x32x16 MFMA, wave tile
// 64x64 = 2x2. Same fragment/swizzle layout as v1 (m74/m101-verified).
// K-loop is the flash-verified 2-phase pipeline: stage(next tile) into buf^1 at
// iter top via gll16, s_waitcnt vmcnt(8) (own current-tile loads done; next's 8
// stay in flight -- NEVER vmcnt(0) mid-loop), raw s_barrier, compute buf, end
// barrier (protects buf^1... buf reuse across iters). Replaces the old
// barrier->stage->barrier(vmcnt0-drain) serial structure (~20% stall, m97).
// CVTA (Wv GEMM): A fp32 -> T14 issue-early/write-late: f32 loads for it+1
// issue at iter top (counted in vmcnt(12)), convert+ds_write AFTER compute,
// lgkmcnt(0) before end barrier makes them visible block-wide.
template <typename OT, bool CVTA>
__global__ __launch_bounds__(256) void gemm_nt(const void* __restrict__ Av,
                                               const u16* __restrict__ B,
                                               OT* __restrict__ C,
                                               int M, int N, int K) {
  __shared__ __align__(16) u16 As[2][128 * 64];
  __shared__ __align__(16) u16 Bs[2][128 * 64];
  const int t  = threadIdx.x;
  const int w  = t >> 6, l = t & 63;
  const int l31 = l & 31, lh = l >> 5;
  const int wr = w >> 1, wc = w & 1;
  const int m0 = blockIdx.y * 128, n0 = blockIdx.x * 128;
  const int nIt = K >> 6;

  f32x4 pa[4], pb[4];  // CVTA prefetch regs (static-indexed via unroll)

  auto stageB = [&](int it) {
    const int k0 = it << 6, sb = it & 1;
#pragma unroll
    for (int i = 0; i < 4; ++i) {
      const int ci = i * 256 + t;
      const int r = ci >> 3, c = ci & 7, gq = c ^ (r & 7);
      gll16(B + (size_t)(n0 + r) * K + k0 + gq * 8, Bs[sb] + ci * 8);
    }
  };
  auto stageA = [&](int it) {
    const u16* A = (const u16*)Av;
    const int k0 = it << 6, sb = it & 1;
#pragma unroll
    for (int i = 0; i < 4; ++i) {
      const int ci = i * 256 + t;
      const int r = ci >> 3, c = ci & 7, gq = c ^ (r & 7);
      gll16(A + (size_t)(m0 + r) * K + k0 + gq * 8, As[sb] + ci * 8);
    }
  };
  auto loadA = [&](int it) {  // CVTA: issue f32 loads only
    const float* A = (const float*)Av;
    const int k0 = it << 6;
#pragma unroll
    for (int i = 0; i < 4; ++i) {
      const int ci = i * 256 + t;
      const int r = ci >> 3, c = ci & 7, gq = c ^ (r & 7);
      const float* s = A + (size_t)(m0 + r) * K + k0 + gq * 8;
      pa[i] = *(const f32x4*)s;
      pb[i] = *(const f32x4*)(s + 4);
    }
  };
  auto writeA = [&](int it) {  // CVTA: convert + ds_write
    const int sb = it & 1;
#pragma unroll
    for (int i = 0; i < 4; ++i) {
      const int ci = i * 256 + t;
      union { u16 u[8]; i32x4 v; } rr;
      rr.u[0] = f2bf(pa[i][0]); rr.u[1] = f2bf(pa[i][1]);
      rr.u[2] = f2bf(pa[i][2]); rr.u[3] = f2bf(pa[i][3]);
      rr.u[4] = f2bf(pb[i][0]); rr.u[5] = f2bf(pb[i][1]);
      rr.u[6] = f2bf(pb[i][2]); rr.u[7] = f2bf(pb[i][3]);
      *(i32x4*)(As[sb] + ci * 8) = rr.v;
    }
  };

  f32x16 acc[2][2];
#pragma unroll
  for (int mi = 0; mi < 2; ++mi)
#pragma unroll
    for (int ni = 0; ni < 2; ++ni)
#pragma unroll
      for (int e = 0; e < 16; ++e) acc[mi][ni][e] = 0.f;

  // prologue: tile 0 into buf0
  if constexpr (CVTA) { loadA(0); stageB(0); writeA(0); }
  else                { stageA(0); stageB(0); }

  for (int it = 0; it < nIt; ++it) {
    const int cb = it & 1;
    if (it + 1 < nIt) {
      if constexpr (CVTA) {
        loadA(it + 1); stageB(it + 1);
        asm volatile("s_waitcnt vmcnt(12) lgkmcnt(0)" ::: "memory");
      } else {
        stageA(it + 1); stageB(it + 1);
        asm volatile("s_waitcnt vmcnt(8)" ::: "memory");
      }
    } else {
      asm volatile("s_waitcnt vmcnt(0) lgkmcnt(0)" ::: "memory");
    }
    asm volatile("s_barrier" ::: "memory");  // buf[cb] fully staged block-wide

    const u16* Ab = As[cb];
    const u16* Bb = Bs[cb];
#pragma unroll
    for (int ks = 0; ks < 4; ++ks) {   // K=16 per step
      const int chunk = ks * 2 + lh;
      s16x8 af[2], bfr[2];
#pragma unroll
      for (int mi = 0; mi < 2; ++mi) {
        const int ra = wr * 64 + mi * 32 + l31;
        af[mi] = *(const s16x8*)(Ab + ra * 64 + ((chunk ^ (ra & 7)) << 3));
      }
#pragma unroll
      for (int ni = 0; ni < 2; ++ni) {
        const int rb = wc * 64 + ni * 32 + l31;
        bfr[ni] = *(const s16x8*)(Bb + rb * 64 + ((chunk ^ (rb & 7)) << 3));
      }
#pragma unroll
      for (int mi = 0; mi < 2; ++mi)
#pragma unroll
        for (int ni = 0; ni < 2; ++ni)
          acc[mi][ni] = __builtin_amdgcn_mfma_f32_32x32x16_bf16(af[mi], bfr[ni], acc[mi][ni], 0, 0, 0);
    }

    if constexpr (CVTA) {
      if (it + 1 < nIt) writeA(it + 1);  // lands in buf^1 while others compute
      asm volatile("s_waitcnt lgkmcnt(0)" ::: "memory");
    }
    asm volatile("s_barrier" ::: "memory");  // buf consumed; next DMA safe
  }

#pragma unroll
  for (int mi = 0; mi < 2; ++mi)
#pragma unroll
    for (int ni = 0; ni < 2; ++ni) {
      const int col = n0 + wc * 64 + ni * 32 + l31;
#pragma unroll
      for (int reg = 0; reg < 16; ++reg) {
        const int row = m0 + wr * 64 + mi * 32 + 4 * lh + (reg & 3) + 8 * (reg >> 2);
        const float v = acc[mi][ni][reg];
        if constexpr (sizeof(OT) == 2) {
          C[(size_t)row * N + col] = (OT)f2bf(v);
        } else {
          C[(size_t)row * N + col] = v;
        }
      }
    }
}

// ---------------- merged Q+K GEMM v2 (same pipeline) ----------------
// grid dim(32,32) = 1024 blocks: bx<16 computes Q tile, bx>=16 computes K tile.
__global__ __launch_bounds__(256) void gemm_qk(const u16* __restrict__ A,
                                               const u16* __restrict__ B0,
                                               const u16* __restrict__ B1,
                                               u16* __restrict__ C0,
                                               u16* __restrict__ C1) {
  constexpr int K = 2048, N = 2048;
  constexpr int nIt = K >> 6;
  __shared__ __align__(16) u16 As[2][128 * 64];
  __shared__ __align__(16) u16 Bs[2][128 * 64];
  const int bx = blockIdx.x;
  const u16* B = (bx >> 4) ? B1 : B0;
  u16* C = (bx >> 4) ? C1 : C0;
  const int n0 = (bx & 15) * 128, m0 = blockIdx.y * 128;
  const int t  = threadIdx.x;
  const int w  = t >> 6, l = t & 63;
  const int l31 = l & 31, lh = l >> 5;
  const int wr = w >> 1, wc = w & 1;

  auto stage = [&](int it) {
    const int k0 = it << 6, sb = it & 1;
#pragma unroll
    for (int i = 0; i < 4; ++i) {
      const int ci = i * 256 + t;
      const int r = ci >> 3, c = ci & 7, gq = c ^ (r & 7);
      gll16(A + (size_t)(m0 + r) * K + k0 + gq * 8, As[sb] + ci * 8);
    }
#pragma unroll
    for (int i = 0; i < 4; ++i) {
      const int ci = i * 256 + t;
      const int r = ci >> 3, c = ci & 7, gq = c ^ (r & 7);
      gll16(B + (size_t)(n0 + r) * K + k0 + gq * 8, Bs[sb] + ci * 8);
    }
  };

  f32x16 acc[2][2];
#pragma unroll
  for (int mi = 0; mi < 2; ++mi)
#pragma unroll
    for (int ni = 0; ni < 2; ++ni)
#pragma unroll
      for (int e = 0; e < 16; ++e) acc[mi][ni][e] = 0.f;

  stage(0);

  for (int it = 0; it < nIt; ++it) {
    const int cb = it & 1;
    if (it + 1 < nIt) {
      stage(it + 1);
      asm volatile("s_waitcnt vmcnt(8)" ::: "memory");
    } else {
      asm volatile("s_waitcnt vmcnt(0)" ::: "memory");
    }
    asm volatile("s_barrier" ::: "memory");

    const u16* Ab = As[cb];
    const u16* Bb = Bs[cb];
#pragma unroll
    for (int ks = 0; ks < 4; ++ks) {
      const int chunk = ks * 2 + lh;
      s16x8 af[2], bfr[2];
#pragma unroll
      for (int mi = 0; mi < 2; ++mi) {
        const int ra = wr * 64 + mi * 32 + l31;
        af[mi] = *(const s16x8*)(Ab + ra * 64 + ((chunk ^ (ra & 7)) << 3));
      }
#pragma unroll
      for (int ni = 0; ni < 2; ++ni) {
        const int rb = wc * 64 + ni * 32 + l31;
        bfr[ni] = *(const s16x8*)(Bb + rb * 64 + ((chunk ^ (rb & 7)) << 3));
      }
#pragma unroll
      for (int mi = 0; mi < 2; ++mi)
#pragma unroll
        for (int ni = 0; ni < 2; ++ni)
          acc[mi][ni] = __builtin_amdgcn_mfma_f32_32x32x16_bf16(af[mi], bfr[ni], acc[mi][ni], 0, 0, 0);
    }

    asm volatile("s_barrier" ::: "memory");
  }

#pragma unroll
  for (int mi = 0; mi < 2; ++mi)
#pragma unroll
    for (int ni = 0; ni < 2; ++ni) {
      const int col = n0 + wc * 64 + ni * 32 + l31;
#pragma unroll
      for (int reg = 0; reg < 16; ++reg) {
        const int row = m0 + wr * 64 + mi * 32 + 4 * lh + (reg & 3) + 8 * (reg >> 2);
        C[(size_t)row * N + col] = f2bf(acc[mi][ni][reg]);
      }
    }
}

// ---------------- RoPE (interleaved) on q and k, in place, bf16 ----------------
// Q is additionally pre-scaled by rsqrt(128)*log2(e): scores arrive in exp2 domain.
__global__ __launch_bounds__(256) void rope_kernel(u16* __restrict__ q, u16* __restrict__ k) {
  const float QS = 0.08838834764831845f * 1.4426950408889634f;
  const size_t t = (size_t)blockIdx.x * 256 + threadIdx.x;
  const size_t e8 = t * 8;
  const int col = (int)(e8 & (E_DIM - 1));
  const int row = (int)(e8 >> 11);
  const int s   = row & (SEQ - 1);
  const int d   = col & (HD - 1);
  float cs[4], sn[4];
#pragma unroll
  for (int j = 0; j < 4; ++j) {
    const float inv = exp2f(-0.20762050593046014f * (float)((d >> 1) + j));
    const float ang = (float)s * inv;
    sincosf(ang, &sn[j], &cs[j]);
  }
  u16* qp = q + e8;
  u16* kp = k + e8;
  union { u16 u[8]; i32x4 v; } a, b;
  a.v = *(const i32x4*)qp;
  b.v = *(const i32x4*)kp;
#pragma unroll
  for (int j = 0; j < 4; ++j) {
    const float csq = cs[j] * QS, snq = sn[j] * QS;
    const float q1 = bf2f(a.u[2 * j]), q2 = bf2f(a.u[2 * j + 1]);
    const float k1 = bf2f(b.u[2 * j]), k2 = bf2f(b.u[2 * j + 1]);
    a.u[2 * j]     = f2bf(q1 * csq - q2 * snq);
    a.u[2 * j + 1] = f2bf(q1 * snq + q2 * csq);
    b.u[2 * j]     = f2bf(k1 * cs[j] - k2 * sn[j]);
    b.u[2 * j + 1] = f2bf(k1 * sn[j] + k2 * cs[j]);
  }
  *(i32x4*)qp = a.v;
  *(i32x4*)kp = b.v;
}

// ---------------- causal flash attention v8 (round-4 verified, unchanged) ------
// KVBLK=128, QBLK=128, grid 256, 17 uniform iters via pair (15-j, j), j=0..7.
// P in a dedicated 16 KiB LDS region (2 barriers/iter); prefetch next KV tile +
// s_waitcnt vmcnt(8) (never 0 mid-loop) + raw s_barrier. LDS 144 KiB.
// XCD-grouped decode: all 8 j-blocks of one (b,h) share bx%8 -> same XCD L2.
__global__ __launch_bounds__(512, 2) void flash_kernel(const u16* __restrict__ q,
                                                       const u16* __restrict__ kmat,
                                                       const u16* __restrict__ vt,
                                                       u16* __restrict__ attn) {
  __shared__ __align__(16) u16 KV[73728];  // 144 KiB: buf0 K|V, buf1 K|V, P
  const int bx = blockIdx.x;
  const int j  = bx >> 5;                        // 0..7  paired-tile index
  const int bh = (bx & 7) * 4 + ((bx >> 3) & 3); // 0..31, constant bx%8 per (b,h)
  const int b  = bh >> 4, h = bh & 15;
  const int t = threadIdx.x, w = t >> 6, l = t & 63, lq = l >> 4, lm = l & 15;

  u16* Pw = KV + 65536 + w * 1024;  // dedicated per-wave 16x64 P slice
  const u16* kbase = kmat + (size_t)(b * SEQ) * E_DIM + h * HD;
  const u16* vbase = vt + (size_t)(h * HD) * BS_TOT + (size_t)b * SEQ;
  const f32x4 fzero = {0.f, 0.f, 0.f, 0.f};

  auto stage = [&](int it) {
    const int base = (it & 1) << 15;  // buffer select (u16 units, 32768 apart)
    const int k0 = it * 128;
#pragma unroll
    for (int i = 0; i < 4; ++i) {     // K tile: 128(s) x 128(d) bf16 = 32 KB
      const int ci = i * 512 + t;
      const int r = ci >> 4, gq = (ci & 15) ^ (r & 15);
      gll16(kbase + (size_t)(k0 + r) * E_DIM + gq * 8, KV + base + ci * 8);
    }
#pragma unroll
    for (int i = 0; i < 4; ++i) {     // V^T tile: 128(d) x 128(s) bf16 = 32 KB
      const int ci = i * 512 + t;
      const int r = ci >> 4, gq = (ci & 15) ^ (r & 15);
      gll16(vbase + (size_t)r * BS_TOT + k0 + gq * 8, KV + base + 16384 + ci * 8);
    }
  };

  for (int pass = 0; pass < 2; ++pass) {
    const int qt = pass ? j : (15 - j);
    const int q0 = qt * 128;
    const int nT = qt + 1;

    stage(0);  // prologue: tile 0 into buf0 (pass 1: after end-of-loop barrier)

    const u16* qp = q + (size_t)(b * SEQ + q0 + w * 16) * E_DIM + h * HD;
    s16x8 qf[4];
#pragma unroll
    for (int kx = 0; kx < 4; ++kx)
      qf[kx] = *(const s16x8*)(qp + (size_t)lm * E_DIM + kx * 32 + lq * 8);

    float m_i[4], l_i[4];
    f32x4 acc_o[8];
#pragma unroll
    for (int rr = 0; rr < 4; ++rr) { m_i[rr] = -1e30f; l_i[rr] = 0.f; }
#pragma unroll
    for (int nd = 0; nd < 8; ++nd) acc_o[nd] = fzero;

    for (int it = 0; it < nT; ++it) {
      const int base = (it & 1) << 15;
      const int k0 = it * 128;
      // prefetch next tile; wait only for OWN tile's 8 loads (counted vmcnt)
      if (it + 1 < nT) {
        stage(it + 1);
        asm volatile("s_waitcnt vmcnt(8)" ::: "memory");
      } else {
        asm volatile("s_waitcnt vmcnt(0)" ::: "memory");
      }
      asm volatile("s_barrier" ::: "memory");  // (a) buf[it&1] staged block-wide

      // S = Q K^T  (per wave: 16 x 128), scores pre-scaled into exp2 domain
      f32x4 sc[8];
#pragma unroll
      for (int ni = 0; ni < 8; ++ni) sc[ni] = fzero;
      __builtin_amdgcn_s_setprio(1);
#pragma unroll
      for (int kx = 0; kx < 4; ++kx) {
        s16x8 kf[8];
#pragma unroll
        for (int ni = 0; ni < 8; ++ni) {
          const int rn = ni * 16 + lm;
          kf[ni] = *(const s16x8*)(KV + base + rn * 128 + (((kx * 4 + lq) ^ lm) << 3));
        }
#pragma unroll
        for (int ni = 0; ni < 8; ++ni)
          sc[ni] = __builtin_amdgcn_mfma_f32_16x16x32_bf16(qf[kx], kf[ni], sc[ni], 0, 0, 0);
      }
      __builtin_amdgcn_s_setprio(0);

      // online softmax (exp2 domain); diag masking on the last tile only
      const bool diag = (it == nT - 1);
#pragma unroll
      for (int rr = 0; rr < 4; ++rr) {
        const int qrow = q0 + w * 16 + lq * 4 + rr;
        float mt = -1e30f;
#pragma unroll
        for (int ni = 0; ni < 8; ++ni) {
          float s = sc[ni][rr];
          if (diag && (k0 + ni * 16 + lm) > qrow) s = -1e30f;
          sc[ni][rr] = s;
          mt = fmaxf(mt, s);
        }
        mt = rmax16(mt);
        const float mn = fmaxf(m_i[rr], mt);
        const float al = exp2f(m_i[rr] - mn);
        float rs = 0.f;
#pragma unroll
        for (int ni = 0; ni < 8; ++ni) {
          const float p = exp2f(sc[ni][rr] - mn);
          sc[ni][rr] = p;
          rs += p;
        }
        rs = rsum16(rs);
        l_i[rr] = l_i[rr] * al + rs;
        m_i[rr] = mn;
#pragma unroll
        for (int nd = 0; nd < 8; ++nd) acc_o[nd][rr] *= al;
      }

      // O += P V in two k-halves through the dedicated per-wave P slice
      // (own-wave write->read, lgkmcnt-ordered; NO block barrier needed)
      __builtin_amdgcn_s_setprio(1);
#pragma unroll
      for (int half = 0; half < 2; ++half) {
#pragma unroll
        for (int rr = 0; rr < 4; ++rr) {
          const int r = lq * 4 + rr;
#pragma unroll
          for (int ni = 0; ni < 4; ++ni) {
            const int c = ni * 16 + lm;
            Pw[r * 64 + (((c >> 3) ^ (r & 7)) << 3) + (c & 7)] =
                f2bf(sc[half * 4 + ni][rr]);
          }
        }
#pragma unroll
        for (int kx = 0; kx < 2; ++kx) {
          const s16x8 pf = *(const s16x8*)(Pw + lm * 64 + (((kx * 4 + lq) ^ (lm & 7)) << 3));
#pragma unroll
          for (int nd = 0; nd < 8; ++nd) {
            const int rn = nd * 16 + lm;
            const s16x8 vf = *(const s16x8*)(KV + base + 16384 + rn * 128 +
                                             (((half * 8 + kx * 4 + lq) ^ lm) << 3));
            acc_o[nd] = __builtin_amdgcn_mfma_f32_16x16x32_bf16(pf, vf, acc_o[nd], 0, 0, 0);
          }
        }
      }
      __builtin_amdgcn_s_setprio(0);

      asm volatile("s_barrier" ::: "memory");  // (c) buf consumed; next stage safe
    }

    // epilogue for this pass: normalize and store bf16
    u16* op = attn + (size_t)(b * SEQ + q0 + w * 16) * E_DIM + h * HD;
#pragma unroll
    for (int rr = 0; rr < 4; ++rr) {
      const float inv = 1.0f / l_i[rr];
      const int row = lq * 4 + rr;
#pragma unroll
      for (int nd = 0; nd < 8; ++nd) {
        const int colc = nd * 16 + lm;
        op[(size_t)row * E_DIM + colc] = f2bf(acc_o[nd][rr] * inv);
      }
    }
  }
}

// ---------------- launch ----------------
// ws 32 MiB: xb @0 (16M, reused as attn), vslot @16M (16M): Wq_bf+Wk_bf copies,
// then V^T (overwrites them), then Wo_bf. d_out scratch: qb @0, kb @+16M.
extern "C" void kernel_launch(void* const* d_in, const int* in_sizes, int n_in,
                              void* d_out, int out_size, void* d_ws, size_t ws_size,
                              hipStream_t stream) {
  const float* x  = (const float*)d_in[0];
  const float* Wq = (const float*)d_in[1];
  const float* Wk = (const float*)d_in[2];
  const float* Wv = (const float*)d_in[3];
  const float* Wo = (const float*)d_in[4];
  float* out = (float*)d_out;
  char* ws = (char*)d_ws;

  u16* xb    = (u16*)(ws);                         // 16 MiB
  u16* vslot = (u16*)(ws + (size_t)16 * 1048576);  // 16 MiB
  u16* wq_bf = vslot;                              // 8 MiB (dead after gemm_qk)
  u16* wk_bf = vslot + (size_t)4 * 1048576;        // 8 MiB (dead after gemm_qk)
  u16* vtb   = vslot;                              // V^T [E][B*S]
  u16* wo_bf = vslot;                              // Wo bf16 (after flash)
  u16* qb    = (u16*)d_out;                        // 16 MiB scratch in d_out
  u16* kb    = (u16*)d_out + (size_t)8 * 1048576;  // 16 MiB scratch in d_out
  u16* attnb = xb;

  (void)in_sizes; (void)n_in; (void)out_size; (void)ws_size;

  cast3_kernel<<<8192, 256, 0, stream>>>(x, xb, Wq, wq_bf, Wk, wk_bf, 4096, 2048);
  gemm_qk<<<dim3(32, 32), 256, 0, stream>>>(xb, wq_bf, wk_bf, qb, kb);
  // V^T[e][s] = Wv[e][:] . x[s][:]  (A = Wv fp32 converted on stage, B = xb)
  gemm_nt<u16, true><<<dim3(32, 16), 256, 0, stream>>>(Wv, xb, vtb, 2048, 4096, 2048);
  rope_kernel<<<4096, 256, 0, stream>>>(qb, kb);
  flash_kernel<<<256, 512, 0, stream>>>(qb, kb, vtb, attnb);
  cast_kernel<<<2048, 256, 0, stream>>>(Wo, wo_bf);
  gemm_nt<float, false><<<dim3(16, 32), 256, 0, stream>>>(attnb, wo_bf, out, 4096, 2048, 2048);
}

// Round 6
// 390.040 us; speedup vs baseline: 1.3766x; 1.0377x over previous
//
#include <hip/hip_runtime.h>
#include <cstdint>
#include <cmath>

typedef short s16x8 __attribute__((ext_vector_type(8)));
typedef float f32x4 __attribute__((ext_vector_type(4)));
typedef float f32x16 __attribute__((ext_vector_type(16)));
typedef int   i32x4 __attribute__((ext_vector_type(4)));
typedef unsigned short u16;

#define E_DIM 2048
#define SEQ   2048
#define NB    2
#define NH    16
#define HD    128
#define BS_TOT 4096   // NB*SEQ

__device__ __forceinline__ u16 f2bf(float f) {
  unsigned u = __float_as_uint(f);
  u += 0x7fffu + ((u >> 16) & 1u);
  return (u16)(u >> 16);
}
__device__ __forceinline__ float bf2f(u16 h) {
  return __uint_as_float(((unsigned)h) << 16);
}
__device__ __forceinline__ float rmax16(float v) {
  v = fmaxf(v, __shfl_xor(v, 1));
  v = fmaxf(v, __shfl_xor(v, 2));
  v = fmaxf(v, __shfl_xor(v, 4));
  v = fmaxf(v, __shfl_xor(v, 8));
  return v;
}
__device__ __forceinline__ float rsum16(float v) {
  v += __shfl_xor(v, 1);
  v += __shfl_xor(v, 2);
  v += __shfl_xor(v, 4);
  v += __shfl_xor(v, 8);
  return v;
}

// async global->LDS, 16B per lane. LDS dest is wave-uniform base + lane*16;
// swizzle goes into the GLOBAL pointer.
__device__ __forceinline__ void gll16(const u16* g, u16* l) {
  __builtin_amdgcn_global_load_lds(
      (const __attribute__((address_space(1))) void*)g,
      (__attribute__((address_space(3))) void*)l, 16, 0, 0);
}

// ---------------- cast fp32 -> bf16, 8 elements/thread ----------------
__global__ __launch_bounds__(256) void cast_kernel(const float* __restrict__ in,
                                                   u16* __restrict__ out) {
  const size_t t = (size_t)blockIdx.x * 256 + threadIdx.x;
  const float* p = in + t * 8;
  f32x4 a = *(const f32x4*)p;
  f32x4 b = *(const f32x4*)(p + 4);
  union { u16 u[8]; i32x4 v; } r;
  r.u[0] = f2bf(a[0]); r.u[1] = f2bf(a[1]); r.u[2] = f2bf(a[2]); r.u[3] = f2bf(a[3]);
  r.u[4] = f2bf(b[0]); r.u[5] = f2bf(b[1]); r.u[6] = f2bf(b[2]); r.u[7] = f2bf(b[3]);
  *(i32x4*)(out + t * 8) = r.v;
}

// three-array cast in one dispatch: [0,n0) -> 0, [n0,n0+n1) -> 1, rest -> 2
__global__ __launch_bounds__(256) void cast3_kernel(const float* __restrict__ in0,
                                                    u16* __restrict__ out0,
                                                    const float* __restrict__ in1,
                                                    u16* __restrict__ out1,
                                                    const float* __restrict__ in2,
                                                    u16* __restrict__ out2,
                                                    int n0, int n1) {
  const int bx = blockIdx.x;
  const float* in; u16* out; int bb;
  if (bx < n0)           { in = in0; out = out0; bb = bx; }
  else if (bx < n0 + n1) { in = in1; out = out1; bb = bx - n0; }
  else                   { in = in2; out = out2; bb = bx - n0 - n1; }
  const size_t t = (size_t)bb * 256 + threadIdx.x;
  const float* p = in + t * 8;
  f32x4 a = *(const f32x4*)p;
  f32x4 b = *(const f32x4*)(p + 4);
  union { u16 u[8]; i32x4 v; } r;
  r.u[0] = f2bf(a[0]); r.u[1] = f2bf(a[1]); r.u[2] = f2bf(a[2]); r.u[3] = f2bf(a[3]);
  r.u[4] = f2bf(b[0]); r.u[5] = f2bf(b[1]); r.u[6] = f2bf(b[2]); r.u[7] = f2bf(b[3]);
  *(i32x4*)(out + t * 8) = r.v;
}

// ---------------- NT GEMM v2: double-buffered counted-vmcnt pipeline ---------
// (unchanged from round 5 -- used for Wv GEMM (CVTA) and the final Wo GEMM)
template <typename OT, bool CVTA>
__global__ __launch_bounds__(256) void gemm_nt(const void* __restrict__ Av,
                                               const u16* __restrict__ B,
                                               OT* __restrict__ C,
                                               int M, int N, int K) {
  __shared__ __align__(16) u16 As[2][128 * 64];
  __shared__ __align__(16) u16 Bs[2][128 * 64];
  const int t  = threadIdx.x;
  const int w  = t >> 6, l = t & 63;
  const int l31 = l & 31, lh = l >> 5;
  const int wr = w >> 1, wc = w & 1;
  const int m0 = blockIdx.y * 128, n0 = blockIdx.x * 128;
  const int nIt = K >> 6;

  f32x4 pa[4], pb[4];  // CVTA prefetch regs (static-indexed via unroll)

  auto stageB = [&](int it) {
    const int k0 = it << 6, sb = it & 1;
#pragma unroll
    for (int i = 0; i < 4; ++i) {
      const int ci = i * 256 + t;
      const int r = ci >> 3, c = ci & 7, gq = c ^ (r & 7);
      gll16(B + (size_t)(n0 + r) * K + k0 + gq * 8, Bs[sb] + ci * 8);
    }
  };
  auto stageA = [&](int it) {
    const u16* A = (const u16*)Av;
    const int k0 = it << 6, sb = it & 1;
#pragma unroll
    for (int i = 0; i < 4; ++i) {
      const int ci = i * 256 + t;
      const int r = ci >> 3, c = ci & 7, gq = c ^ (r & 7);
      gll16(A + (size_t)(m0 + r) * K + k0 + gq * 8, As[sb] + ci * 8);
    }
  };
  auto loadA = [&](int it) {  // CVTA: issue f32 loads only
    const float* A = (const float*)Av;
    const int k0 = it << 6;
#pragma unroll
    for (int i = 0; i < 4; ++i) {
      const int ci = i * 256 + t;
      const int r = ci >> 3, c = ci & 7, gq = c ^ (r & 7);
      const float* s = A + (size_t)(m0 + r) * K + k0 + gq * 8;
      pa[i] = *(const f32x4*)s;
      pb[i] = *(const f32x4*)(s + 4);
    }
  };
  auto writeA = [&](int it) {  // CVTA: convert + ds_write
    const int sb = it & 1;
#pragma unroll
    for (int i = 0; i < 4; ++i) {
      const int ci = i * 256 + t;
      union { u16 u[8]; i32x4 v; } rr;
      rr.u[0] = f2bf(pa[i][0]); rr.u[1] = f2bf(pa[i][1]);
      rr.u[2] = f2bf(pa[i][2]); rr.u[3] = f2bf(pa[i][3]);
      rr.u[4] = f2bf(pb[i][0]); rr.u[5] = f2bf(pb[i][1]);
      rr.u[6] = f2bf(pb[i][2]); rr.u[7] = f2bf(pb[i][3]);
      *(i32x4*)(As[sb] + ci * 8) = rr.v;
    }
  };

  f32x16 acc[2][2];
#pragma unroll
  for (int mi = 0; mi < 2; ++mi)
#pragma unroll
    for (int ni = 0; ni < 2; ++ni)
#pragma unroll
      for (int e = 0; e < 16; ++e) acc[mi][ni][e] = 0.f;

  // prologue: tile 0 into buf0
  if constexpr (CVTA) { loadA(0); stageB(0); writeA(0); }
  else                { stageA(0); stageB(0); }

  for (int it = 0; it < nIt; ++it) {
    const int cb = it & 1;
    if (it + 1 < nIt) {
      if constexpr (CVTA) {
        loadA(it + 1); stageB(it + 1);
        asm volatile("s_waitcnt vmcnt(12) lgkmcnt(0)" ::: "memory");
      } else {
        stageA(it + 1); stageB(it + 1);
        asm volatile("s_waitcnt vmcnt(8)" ::: "memory");
      }
    } else {
      asm volatile("s_waitcnt vmcnt(0) lgkmcnt(0)" ::: "memory");
    }
    asm volatile("s_barrier" ::: "memory");  // buf[cb] fully staged block-wide

    const u16* Ab = As[cb];
    const u16* Bb = Bs[cb];
#pragma unroll
    for (int ks = 0; ks < 4; ++ks) {   // K=16 per step
      const int chunk = ks * 2 + lh;
      s16x8 af[2], bfr[2];
#pragma unroll
      for (int mi = 0; mi < 2; ++mi) {
        const int ra = wr * 64 + mi * 32 + l31;
        af[mi] = *(const s16x8*)(Ab + ra * 64 + ((chunk ^ (ra & 7)) << 3));
      }
#pragma unroll
      for (int ni = 0; ni < 2; ++ni) {
        const int rb = wc * 64 + ni * 32 + l31;
        bfr[ni] = *(const s16x8*)(Bb + rb * 64 + ((chunk ^ (rb & 7)) << 3));
      }
#pragma unroll
      for (int mi = 0; mi < 2; ++mi)
#pragma unroll
        for (int ni = 0; ni < 2; ++ni)
          acc[mi][ni] = __builtin_amdgcn_mfma_f32_32x32x16_bf16(af[mi], bfr[ni], acc[mi][ni], 0, 0, 0);
    }

    if constexpr (CVTA) {
      if (it + 1 < nIt) writeA(it + 1);  // lands in buf^1 while others compute
      asm volatile("s_waitcnt lgkmcnt(0)" ::: "memory");
    }
    asm volatile("s_barrier" ::: "memory");  // buf consumed; next DMA safe
  }

#pragma unroll
  for (int mi = 0; mi < 2; ++mi)
#pragma unroll
    for (int ni = 0; ni < 2; ++ni) {
      const int col = n0 + wc * 64 + ni * 32 + l31;
#pragma unroll
      for (int reg = 0; reg < 16; ++reg) {
        const int row = m0 + wr * 64 + mi * 32 + 4 * lh + (reg & 3) + 8 * (reg >> 2);
        const float v = acc[mi][ni][reg];
        if constexpr (sizeof(OT) == 2) {
          C[(size_t)row * N + col] = (OT)f2bf(v);
        } else {
          C[(size_t)row * N + col] = v;
        }
      }
    }
}

// ---------------- merged Q+K GEMM v3: 256^2 tile, 8 waves, phase-split ------
// BM=BN=256, BK=64, 8 waves (2M x 4N), wave tile 128x64, acc 4x2 f32x16
// (128 VGPR). 32x32x16 MFMA, same verified fragment layout + chunk swizzle.
// Rationale: 256^2 halves L2/L3 panel re-read traffic vs 128^2 (1 GB -> 512 MB
// across both GEMMs -- gemm_qk was cache-BW-bound at ~90us). LDS 128 KiB
// (2 dbuf x (A 32K | B 32K)) -> 1 block/CU, 2 waves/SIMD.
// K-loop keeps the verified counted-vmcnt pipeline (stage next tile, vmcnt(8),
// barrier) and splits compute into 2 phases per K-tile ({ks0,1},{ks2,3}), each
// a setprio(1)-wrapped 16-MFMA cluster with an inter-phase s_barrier: creates
// the wave role-split that makes setprio pay (T5, m218b) -- waves alternate
// {ds_read-issuing} vs {MFMA-executing} roles across the barrier.
// Grid 256 blocks (= 1/CU): decode via XCD-bijective swizzle (bid&7 = xcd).
__global__ __launch_bounds__(512, 1) void gemm_qk(const u16* __restrict__ A,
                                                  const u16* __restrict__ B0,
                                                  const u16* __restrict__ B1,
                                                  u16* __restrict__ C0,
                                                  u16* __restrict__ C1) {
  constexpr int K = 2048, N = 2048;
  constexpr int nIt = K >> 6;  // 32
  __shared__ __align__(16) u16 As[2][256 * 64];  // 64 KiB
  __shared__ __align__(16) u16 Bs[2][256 * 64];  // 64 KiB
  // bijective XCD-grouped decode: logical = (bid&7)*32 + (bid>>3)
  const int logical = (blockIdx.x & 7) * 32 + (blockIdx.x >> 3);
  const u16* B = (logical >> 7) ? B1 : B0;
  u16* C = (logical >> 7) ? C1 : C0;
  const int r7 = logical & 127;
  const int m0 = (r7 >> 3) * 256;   // 16 m-tiles
  const int n0 = (r7 & 7) * 256;    // 8 n-tiles
  const int t  = threadIdx.x;
  const int w  = t >> 6, l = t & 63;
  const int l31 = l & 31, lh = l >> 5;
  const int wr = w >> 2, wc = w & 3;  // 2M x 4N

  auto stage = [&](int it) {
    const int k0 = it << 6, sb = it & 1;
#pragma unroll
    for (int i = 0; i < 4; ++i) {   // A: 256x64 bf16 = 32 KB
      const int ci = i * 512 + t;
      const int r = ci >> 3, c = ci & 7, gq = c ^ (r & 7);
      gll16(A + (size_t)(m0 + r) * K + k0 + gq * 8, As[sb] + ci * 8);
    }
#pragma unroll
    for (int i = 0; i < 4; ++i) {   // B: 256x64 bf16 = 32 KB
      const int ci = i * 512 + t;
      const int r = ci >> 3, c = ci & 7, gq = c ^ (r & 7);
      gll16(B + (size_t)(n0 + r) * K + k0 + gq * 8, Bs[sb] + ci * 8);
    }
  };

  f32x16 acc[4][2];
#pragma unroll
  for (int mi = 0; mi < 4; ++mi)
#pragma unroll
    for (int ni = 0; ni < 2; ++ni)
#pragma unroll
      for (int e = 0; e < 16; ++e) acc[mi][ni][e] = 0.f;

  stage(0);

  for (int it = 0; it < nIt; ++it) {
    const int cb = it & 1;
    if (it + 1 < nIt) {
      stage(it + 1);
      asm volatile("s_waitcnt vmcnt(8)" ::: "memory");
    } else {
      asm volatile("s_waitcnt vmcnt(0)" ::: "memory");
    }
    asm volatile("s_barrier" ::: "memory");  // buf[cb] fully staged block-wide

    const u16* Ab = As[cb];
    const u16* Bb = Bs[cb];
#pragma unroll
    for (int ph = 0; ph < 2; ++ph) {   // 2 phases x (2 ks) per K-tile
#pragma unroll
      for (int ks2 = 0; ks2 < 2; ++ks2) {
        const int ks = ph * 2 + ks2;
        const int chunk = ks * 2 + lh;
        s16x8 af[4], bfr[2];
#pragma unroll
        for (int mi = 0; mi < 4; ++mi) {
          const int ra = wr * 128 + mi * 32 + l31;
          af[mi] = *(const s16x8*)(Ab + ra * 64 + ((chunk ^ (ra & 7)) << 3));
        }
#pragma unroll
        for (int ni = 0; ni < 2; ++ni) {
          const int rb = wc * 64 + ni * 32 + l31;
          bfr[ni] = *(const s16x8*)(Bb + rb * 64 + ((chunk ^ (rb & 7)) << 3));
        }
        __builtin_amdgcn_s_setprio(1);
#pragma unroll
        for (int mi = 0; mi < 4; ++mi)
#pragma unroll
          for (int ni = 0; ni < 2; ++ni)
            acc[mi][ni] = __builtin_amdgcn_mfma_f32_32x32x16_bf16(af[mi], bfr[ni], acc[mi][ni], 0, 0, 0);
        __builtin_amdgcn_s_setprio(0);
      }
      if (ph == 0)
        asm volatile("s_barrier" ::: "memory");  // role-split alignment only
    }

    asm volatile("s_barrier" ::: "memory");  // buf consumed; next DMA safe
  }

#pragma unroll
  for (int mi = 0; mi < 4; ++mi)
#pragma unroll
    for (int ni = 0; ni < 2; ++ni) {
      const int col = n0 + wc * 64 + ni * 32 + l31;
#pragma unroll
      for (int reg = 0; reg < 16; ++reg) {
        const int row = m0 + wr * 128 + mi * 32 + 4 * lh + (reg & 3) + 8 * (reg >> 2);
        C[(size_t)row * N + col] = f2bf(acc[mi][ni][reg]);
      }
    }
}

// ---------------- RoPE (interleaved) on q and k, in place, bf16 ----------------
// Q is additionally pre-scaled by rsqrt(128)*log2(e): scores arrive in exp2 domain.
__global__ __launch_bounds__(256) void rope_kernel(u16* __restrict__ q, u16* __restrict__ k) {
  const float QS = 0.08838834764831845f * 1.4426950408889634f;
  const size_t t = (size_t)blockIdx.x * 256 + threadIdx.x;
  const size_t e8 = t * 8;
  const int col = (int)(e8 & (E_DIM - 1));
  const int row = (int)(e8 >> 11);
  const int s   = row & (SEQ - 1);
  const int d   = col & (HD - 1);
  float cs[4], sn[4];
#pragma unroll
  for (int j = 0; j < 4; ++j) {
    const float inv = exp2f(-0.20762050593046014f * (float)((d >> 1) + j));
    const float ang = (float)s * inv;
    sincosf(ang, &sn[j], &cs[j]);
  }
  u16* qp = q + e8;
  u16* kp = k + e8;
  union { u16 u[8]; i32x4 v; } a, b;
  a.v = *(const i32x4*)qp;
  b.v = *(const i32x4*)kp;
#pragma unroll
  for (int j = 0; j < 4; ++j) {
    const float csq = cs[j] * QS, snq = sn[j] * QS;
    const float q1 = bf2f(a.u[2 * j]), q2 = bf2f(a.u[2 * j + 1]);
    const float k1 = bf2f(b.u[2 * j]), k2 = bf2f(b.u[2 * j + 1]);
    a.u[2 * j]     = f2bf(q1 * csq - q2 * snq);
    a.u[2 * j + 1] = f2bf(q1 * snq + q2 * csq);
    b.u[2 * j]     = f2bf(k1 * cs[j] - k2 * sn[j]);
    b.u[2 * j + 1] = f2bf(k1 * sn[j] + k2 * cs[j]);
  }
  *(i32x4*)qp = a.v;
  *(i32x4*)kp = b.v;
}

// ---------------- causal flash attention v8 (round-4 verified, unchanged) ------
// KVBLK=128, QBLK=128, grid 256, 17 uniform iters via pair (15-j, j), j=0..7.
// P in a dedicated 16 KiB LDS region (2 barriers/iter); prefetch next KV tile +
// s_waitcnt vmcnt(8) (never 0 mid-loop) + raw s_barrier. LDS 144 KiB.
// XCD-grouped decode: all 8 j-blocks of one (b,h) share bx%8 -> same XCD L2.
__global__ __launch_bounds__(512, 2) void flash_kernel(const u16* __restrict__ q,
                                                       const u16* __restrict__ kmat,
                                                       const u16* __restrict__ vt,
                                                       u16* __restrict__ attn) {
  __shared__ __align__(16) u16 KV[73728];  // 144 KiB: buf0 K|V, buf1 K|V, P
  const int bx = blockIdx.x;
  const int j  = bx >> 5;                        // 0..7  paired-tile index
  const int bh = (bx & 7) * 4 + ((bx >> 3) & 3); // 0..31, constant bx%8 per (b,h)
  const int b  = bh >> 4, h = bh & 15;
  const int t = threadIdx.x, w = t >> 6, l = t & 63, lq = l >> 4, lm = l & 15;

  u16* Pw = KV + 65536 + w * 1024;  // dedicated per-wave 16x64 P slice
  const u16* kbase = kmat + (size_t)(b * SEQ) * E_DIM + h * HD;
  const u16* vbase = vt + (size_t)(h * HD) * BS_TOT + (size_t)b * SEQ;
  const f32x4 fzero = {0.f, 0.f, 0.f, 0.f};

  auto stage = [&](int it) {
    const int base = (it & 1) << 15;  // buffer select (u16 units, 32768 apart)
    const int k0 = it * 128;
#pragma unroll
    for (int i = 0; i < 4; ++i) {     // K tile: 128(s) x 128(d) bf16 = 32 KB
      const int ci = i * 512 + t;
      const int r = ci >> 4, gq = (ci & 15) ^ (r & 15);
      gll16(kbase + (size_t)(k0 + r) * E_DIM + gq * 8, KV + base + ci * 8);
    }
#pragma unroll
    for (int i = 0; i < 4; ++i) {     // V^T tile: 128(d) x 128(s) bf16 = 32 KB
      const int ci = i * 512 + t;
      const int r = ci >> 4, gq = (ci & 15) ^ (r & 15);
      gll16(vbase + (size_t)r * BS_TOT + k0 + gq * 8, KV + base + 16384 + ci * 8);
    }
  };

  for (int pass = 0; pass < 2; ++pass) {
    const int qt = pass ? j : (15 - j);
    const int q0 = qt * 128;
    const int nT = qt + 1;

    stage(0);  // prologue: tile 0 into buf0 (pass 1: after end-of-loop barrier)

    const u16* qp = q + (size_t)(b * SEQ + q0 + w * 16) * E_DIM + h * HD;
    s16x8 qf[4];
#pragma unroll
    for (int kx = 0; kx < 4; ++kx)
      qf[kx] = *(const s16x8*)(qp + (size_t)lm * E_DIM + kx * 32 + lq * 8);

    float m_i[4], l_i[4];
    f32x4 acc_o[8];
#pragma unroll
    for (int rr = 0; rr < 4; ++rr) { m_i[rr] = -1e30f; l_i[rr] = 0.f; }
#pragma unroll
    for (int nd = 0; nd < 8; ++nd) acc_o[nd] = fzero;

    for (int it = 0; it < nT; ++it) {
      const int base = (it & 1) << 15;
      const int k0 = it * 128;
      // prefetch next tile; wait only for OWN tile's 8 loads (counted vmcnt)
      if (it + 1 < nT) {
        stage(it + 1);
        asm volatile("s_waitcnt vmcnt(8)" ::: "memory");
      } else {
        asm volatile("s_waitcnt vmcnt(0)" ::: "memory");
      }
      asm volatile("s_barrier" ::: "memory");  // (a) buf[it&1] staged block-wide

      // S = Q K^T  (per wave: 16 x 128), scores pre-scaled into exp2 domain
      f32x4 sc[8];
#pragma unroll
      for (int ni = 0; ni < 8; ++ni) sc[ni] = fzero;
      __builtin_amdgcn_s_setprio(1);
#pragma unroll
      for (int kx = 0; kx < 4; ++kx) {
        s16x8 kf[8];
#pragma unroll
        for (int ni = 0; ni < 8; ++ni) {
          const int rn = ni * 16 + lm;
          kf[ni] = *(const s16x8*)(KV + base + rn * 128 + (((kx * 4 + lq) ^ lm) << 3));
        }
#pragma unroll
        for (int ni = 0; ni < 8; ++ni)
          sc[ni] = __builtin_amdgcn_mfma_f32_16x16x32_bf16(qf[kx], kf[ni], sc[ni], 0, 0, 0);
      }
      __builtin_amdgcn_s_setprio(0);

      // online softmax (exp2 domain); diag masking on the last tile only
      const bool diag = (it == nT - 1);
#pragma unroll
      for (int rr = 0; rr < 4; ++rr) {
        const int qrow = q0 + w * 16 + lq * 4 + rr;
        float mt = -1e30f;
#pragma unroll
        for (int ni = 0; ni < 8; ++ni) {
          float s = sc[ni][rr];
          if (diag && (k0 + ni * 16 + lm) > qrow) s = -1e30f;
          sc[ni][rr] = s;
          mt = fmaxf(mt, s);
        }
        mt = rmax16(mt);
        const float mn = fmaxf(m_i[rr], mt);
        const float al = exp2f(m_i[rr] - mn);
        float rs = 0.f;
#pragma unroll
        for (int ni = 0; ni < 8; ++ni) {
          const float p = exp2f(sc[ni][rr] - mn);
          sc[ni][rr] = p;
          rs += p;
        }
        rs = rsum16(rs);
        l_i[rr] = l_i[rr] * al + rs;
        m_i[rr] = mn;
#pragma unroll
        for (int nd = 0; nd < 8; ++nd) acc_o[nd][rr] *= al;
      }

      // O += P V in two k-halves through the dedicated per-wave P slice
      // (own-wave write->read, lgkmcnt-ordered; NO block barrier needed)
      __builtin_amdgcn_s_setprio(1);
#pragma unroll
      for (int half = 0; half < 2; ++half) {
#pragma unroll
        for (int rr = 0; rr < 4; ++rr) {
          const int r = lq * 4 + rr;
#pragma unroll
          for (int ni = 0; ni < 4; ++ni) {
            const int c = ni * 16 + lm;
            Pw[r * 64 + (((c >> 3) ^ (r & 7)) << 3) + (c & 7)] =
                f2bf(sc[half * 4 + ni][rr]);
          }
        }
#pragma unroll
        for (int kx = 0; kx < 2; ++kx) {
          const s16x8 pf = *(const s16x8*)(Pw + lm * 64 + (((kx * 4 + lq) ^ (lm & 7)) << 3));
#pragma unroll
          for (int nd = 0; nd < 8; ++nd) {
            const int rn = nd * 16 + lm;
            const s16x8 vf = *(const s16x8*)(KV + base + 16384 + rn * 128 +
                                             (((half * 8 + kx * 4 + lq) ^ lm) << 3));
            acc_o[nd] = __builtin_amdgcn_mfma_f32_16x16x32_bf16(pf, vf, acc_o[nd], 0, 0, 0);
          }
        }
      }
      __builtin_amdgcn_s_setprio(0);

      asm volatile("s_barrier" ::: "memory");  // (c) buf consumed; next stage safe
    }

    // epilogue for this pass: normalize and store bf16
    u16* op = attn + (size_t)(b * SEQ + q0 + w * 16) * E_DIM + h * HD;
#pragma unroll
    for (int rr = 0; rr < 4; ++rr) {
      const float inv = 1.0f / l_i[rr];
      const int row = lq * 4 + rr;
#pragma unroll
      for (int nd = 0; nd < 8; ++nd) {
        const int colc = nd * 16 + lm;
        op[(size_t)row * E_DIM + colc] = f2bf(acc_o[nd][rr] * inv);
      }
    }
  }
}

// ---------------- launch ----------------
// ws 32 MiB: xb @0 (16M, reused as attn), vslot @16M (16M): Wq_bf+Wk_bf copies,
// then V^T (overwrites them), then Wo_bf. d_out scratch: qb @0, kb @+16M.
extern "C" void kernel_launch(void* const* d_in, const int* in_sizes, int n_in,
                              void* d_out, int out_size, void* d_ws, size_t ws_size,
                              hipStream_t stream) {
  const float* x  = (const float*)d_in[0];
  const float* Wq = (const float*)d_in[1];
  const float* Wk = (const float*)d_in[2];
  const float* Wv = (const float*)d_in[3];
  const float* Wo = (const float*)d_in[4];
  float* out = (float*)d_out;
  char* ws = (char*)d_ws;

  u16* xb    = (u16*)(ws);                         // 16 MiB
  u16* vslot = (u16*)(ws + (size_t)16 * 1048576);  // 16 MiB
  u16* wq_bf = vslot;                              // 8 MiB (dead after gemm_qk)
  u16* wk_bf = vslot + (size_t)4 * 1048576;        // 8 MiB (dead after gemm_qk)
  u16* vtb   = vslot;                              // V^T [E][B*S]
  u16* wo_bf = vslot;                              // Wo bf16 (after flash)
  u16* qb    = (u16*)d_out;                        // 16 MiB scratch in d_out
  u16* kb    = (u16*)d_out + (size_t)8 * 1048576;  // 16 MiB scratch in d_out
  u16* attnb = xb;

  (void)in_sizes; (void)n_in; (void)out_size; (void)ws_size;

  cast3_kernel<<<8192, 256, 0, stream>>>(x, xb, Wq, wq_bf, Wk, wk_bf, 4096, 2048);
  gemm_qk<<<256, 512, 0, stream>>>(xb, wq_bf, wk_bf, qb, kb);
  // V^T[e][s] = Wv[e][:] . x[s][:]  (A = Wv fp32 converted on stage, B = xb)
  gemm_nt<u16, true><<<dim3(32, 16), 256, 0, stream>>>(Wv, xb, vtb, 2048, 4096, 2048);
  rope_kernel<<<4096, 256, 0, stream>>>(qb, kb);
  flash_kernel<<<256, 512, 0, stream>>>(qb, kb, vtb, attnb);
  cast_kernel<<<2048, 256, 0, stream>>>(Wo, wo_bf);
  gemm_nt<float, false><<<dim3(16, 32), 256, 0, stream>>>(attnb, wo_bf, out, 4096, 2048, 2048);
}